// Round 12
// baseline (201.666 us; speedup 1.0000x reference)
//
#include <hip/hip_runtime.h>
#include <hip/hip_bf16.h>
#include <stdint.h>

#define DIM 1024
#define SEQ 2048
#define NB 4
#define HEADS 8
#define HD 128
#define ROWS (NB*SEQ)   // 8192

typedef __attribute__((ext_vector_type(8))) short bf16x8;
typedef __attribute__((ext_vector_type(4))) float f32x4;

#define VMCNT(n) asm volatile("s_waitcnt vmcnt(" #n ")" ::: "memory")
#define SBAR()   __builtin_amdgcn_s_barrier()
#define SCHED0() __builtin_amdgcn_sched_barrier(0)

static __device__ __forceinline__ unsigned short f2bf(float f){
  union { float f; unsigned int u; } x; x.f = f;
  unsigned int r = x.u + 0x7fffu + ((x.u >> 16) & 1u);
  return (unsigned short)(r >> 16);
}

static __device__ __forceinline__ void gld_lds16(const void* g, void* l){
  __builtin_amdgcn_global_load_lds(
      (const __attribute__((address_space(1))) void*)g,
      (__attribute__((address_space(3))) void*)l,
      16, 0, 0);
}

// ---------------- prep0: cast x | transpose 3 weights ----------------
__global__ void k_prep0(const float* __restrict__ x,
                        const float* __restrict__ Wk, const float* __restrict__ Wv,
                        const float* __restrict__ Wo,
                        unsigned short* __restrict__ xb,
                        unsigned short* __restrict__ Tk, unsigned short* __restrict__ Tv,
                        unsigned short* __restrict__ To){
  __shared__ float tile[64][65];
  const int B = blockIdx.x;
  const int tid = threadIdx.x;
  if (B < 2048){
    for (int i = B*256 + tid; i < ROWS*DIM/4; i += 2048*256){
      const float4 v = reinterpret_cast<const float4*>(x)[i];
      ushort4 o;
      o.x = f2bf(v.x); o.y = f2bf(v.y); o.z = f2bf(v.z); o.w = f2bf(v.w);
      reinterpret_cast<ushort4*>(xb)[i] = o;
    }
  } else {
    const int D = B - 2048;
    const int z = D >> 8;
    const int rem = D & 255;
    const int bo = (rem & 15) * 64;
    const int bi = (rem >> 4) * 64;
    const float* W = (z == 0) ? Wk : (z == 1) ? Wv : Wo;
    unsigned short* WT = (z == 0) ? Tk : (z == 1) ? Tv : To;
    #pragma unroll
    for (int it = 0; it < 16; ++it){
      int f = it*256 + tid;
      int r = f >> 6, c = f & 63;
      tile[r][c] = W[(size_t)(bi + r) * DIM + bo + c];
    }
    __syncthreads();
    #pragma unroll
    for (int it = 0; it < 16; ++it){
      int f = it*256 + tid;
      int r = f >> 6, c = f & 63;
      WT[(size_t)(bo + r) * DIM + bi + c] = f2bf(tile[c][r]);
    }
  }
}

// ---------------- fused K/V projection (BK=32, 64KB LDS) + co-resident ew blocks ----------
// Blocks [0,256): proj. Blocks [256,512): ew (exp(w_aft) causal -> ewb), 64 rows each.
// proj: BM=256, B = 128 k-cols | 128 v-cols. LDS packed rows of 128B:
//   A slot [128 r'][xhalf*64B | kb], r'=R&127, xhalf=R>>7 (R = x row - row0)
//   B slot [128 r'][wkt 64B | wvt 64B], r' = weight col - col0k
// Swizzle: LDS[r'][c] holds global byte c ^ ((r'&7)<<4)  (both-sides, rule 21).
// 32 K-tiles x 4 phases; stage 1 unit (1 gld/thread)/phase; VMCNT(1) at q0 only.
__global__ __launch_bounds__(512) void k_projew(
    const unsigned short* __restrict__ xb,
    const unsigned short* __restrict__ wkt,
    const unsigned short* __restrict__ wvt,
    const float* __restrict__ bk,
    const float* __restrict__ bv,
    const float* __restrict__ waft,
    unsigned short* __restrict__ ekb,
    unsigned short* __restrict__ ewb)
{
  __shared__ __align__(16) char smem[65536];

  if (blockIdx.x >= 256){
    // ---------- ew path (no LDS use) ----------
    const int base = (blockIdx.x - 256) * 64;
    for (int rr = 0; rr < 64; ++rr){
      const int row = base + rr;
      const int t = row & 2047;
      const int h = row >> 11;
      const float* src = waft + ((size_t)h*SEQ + t) * SEQ;
      unsigned short* dst = ewb + ((size_t)h*SEQ + t) * SEQ;
      const int smax4 = ((t & ~127) + 128) >> 2;
      for (int i = threadIdx.x; i < smax4; i += 512){
        const float4 w4 = reinterpret_cast<const float4*>(src)[i];
        const int s = i * 4;
        ushort4 o;
        o.x = (s+0 <= t) ? f2bf(__expf(w4.x)) : (unsigned short)0;
        o.y = (s+1 <= t) ? f2bf(__expf(w4.y)) : (unsigned short)0;
        o.z = (s+2 <= t) ? f2bf(__expf(w4.z)) : (unsigned short)0;
        o.w = (s+3 <= t) ? f2bf(__expf(w4.w)) : (unsigned short)0;
        reinterpret_cast<ushort4*>(dst)[i] = o;
      }
    }
    return;
  }

  // ---------- proj path ----------
  unsigned short* Asl = (unsigned short*)smem;            // [2][128*64] = 2x16KB
  unsigned short* Bsl = (unsigned short*)(smem + 32768);  // [2][128*64] = 2x16KB
  float* xch = (float*)smem;                              // epilogue [256][64] f32 = 64KB

  const int tid  = threadIdx.x;
  const int lane = tid & 63;
  const int lo   = lane & 15;
  const int hi   = lane >> 4;
  const int wid  = tid >> 6;
  const int wm   = wid >> 2;       // 0..1 : row half
  const int wn   = wid & 3;        // 0,1 = k cols; 2,3 = v cols
  const int D    = blockIdx.x;
  const int row0 = (D >> 3) * 256;
  const int col0k = (D & 7) * 128;

  f32x4 acc[8][4] = {};

  // unit u: 0,1 = A r' ranges [0,64),[64,128); 2,3 = B same
  auto stage_unit = [&](int kt, int slot, int u){
    const int po   = tid * 16;
    const int rloc = (po >> 7) + (u & 1) * 64;    // r' in [0,128)
    const int cg   = (po & 127) ^ ((rloc & 7) << 4);
    const int half = cg >> 6;
    const int kb   = cg & 63;
    if (u < 2){
      const unsigned short* src = xb + (size_t)(row0 + half*128 + rloc)*DIM + kt*32 + (kb >> 1);
      gld_lds16(src, (char*)Asl + slot*16384 + (u & 1)*8192 + po);
    } else {
      const unsigned short* wsrc = half ? wvt : wkt;
      const unsigned short* src = wsrc + (size_t)(col0k + rloc)*DIM + kt*32 + (kb >> 1);
      gld_lds16(src, (char*)Bsl + slot*16384 + (u & 1)*8192 + po);
    }
  };

  #pragma unroll
  for (int u = 0; u < 4; ++u) stage_unit(0, 0, u);

  for (int t = 0; t < 32; ++t){
    const int s = t & 1;
    const char* Ab = (const char*)Asl + s*16384;
    const char* Bb = (const char*)Bsl + s*16384;
    #pragma unroll
    for (int q = 0; q < 4; ++q){
      if (t + 1 < 32) stage_unit(t + 1, s ^ 1, q);
      if (q == 0){
        if (t + 1 < 32) { VMCNT(1); } else { VMCNT(0); }
      }
      SCHED0();
      SBAR();
      SCHED0();
      bf16x8 a[2], b[4];
      #pragma unroll
      for (int mf2 = 0; mf2 < 2; ++mf2){
        const int rp = (q*2 + mf2)*16 + lo;       // r' = R&127 (R = wm*128 + rp)
        a[mf2] = *reinterpret_cast<const bf16x8*>(
            Ab + rp*128 + ((wm*64 + hi*16) ^ ((rp & 7) << 4)));
      }
      #pragma unroll
      for (int nf = 0; nf < 4; ++nf){
        const int rp = (wn & 1)*64 + nf*16 + lo;  // r' of B row
        b[nf] = *reinterpret_cast<const bf16x8*>(
            Bb + rp*128 + (((wn >> 1)*64 + hi*16) ^ ((rp & 7) << 4)));
      }
      __builtin_amdgcn_s_setprio(1);
      #pragma unroll
      for (int mf2 = 0; mf2 < 2; ++mf2)
        #pragma unroll
        for (int nf = 0; nf < 4; ++nf)
          acc[q*2+mf2][nf] = __builtin_amdgcn_mfma_f32_16x16x32_bf16(
              a[mf2], b[nf], acc[q*2+mf2][nf], 0, 0, 0);
      __builtin_amdgcn_s_setprio(0);
      SCHED0();
      SBAR();
    }
  }

  // ---- epilogue: two exchange rounds (e=0: wave wn==2 -> wn==0; e=1: wn==3 -> wn==1) ----
  #pragma unroll
  for (int e = 0; e < 2; ++e){
    __syncthreads();
    if (wn == 2 + e){
      #pragma unroll
      for (int mf = 0; mf < 8; ++mf){
        const int rloc = wm*128 + mf*16 + hi*4;
        #pragma unroll
        for (int nf = 0; nf < 4; ++nf){
          const int cv = nf*16 + lo;              // local col 0..63
          #pragma unroll
          for (int jj = 0; jj < 4; ++jj)
            xch[(size_t)(rloc + jj)*64 + cv] = acc[mf][nf][jj];
        }
      }
    }
    __syncthreads();
    if (wn == e){
      #pragma unroll
      for (int nf = 0; nf < 4; ++nf){
        const int ck = nf*16 + lo;                // local col 0..63
        const int c  = col0k + wn*64 + ck;        // global k col
        const int h  = c >> 7;
        const int d  = c & 127;
        const float bkc = bk[c];
        const float bvc = bv[c];
        #pragma unroll
        for (int mf = 0; mf < 8; ++mf){
          const int rloc = wm*128 + mf*16 + hi*4;
          const int r = row0 + rloc;
          const int n = r >> 11;
          const int sidx = r & 2047;
          ushort4 pk, pv;
          #pragma unroll
          for (int jj = 0; jj < 4; ++jj){
            const float kval = acc[mf][nf][jj] + bkc;
            const float vval = xch[(size_t)(rloc + jj)*64 + ck] + bvc;
            const float ek = __expf(kval);
            ((unsigned short*)&pk)[jj] = f2bf(ek);
            ((unsigned short*)&pv)[jj] = f2bf(ek * vval);
          }
          const size_t idx = ((size_t)h*1024 + n*256 + d) * SEQ + sidx;
          *reinterpret_cast<ushort4*>(&ekb[idx]) = pk;
          *reinterpret_cast<ushort4*>(&ekb[idx + (size_t)128*SEQ]) = pv;
        }
      }
    }
  }
}

// ---------------- AFT causal core: 8-phase, BM=128 BN=256 (den|num), fused division ----------
// (R9/R11 proven version: uniform 34 K-steps/block via triangle pairing {15-p, p})
__global__ __launch_bounds__(512) void k_core(
    const unsigned short* __restrict__ ewb,
    const unsigned short* __restrict__ ekb,
    unsigned short* __restrict__ aftb)
{
  __shared__ __align__(16) char smem[98304];              // A[2][128*64] + B[2][256*64]
  unsigned short* Asl = (unsigned short*)smem;            // 32 KB
  unsigned short* Bsl = (unsigned short*)(smem + 32768);  // 64 KB
  float* xch = (float*)smem;                              // epilogue [128][129] f32

  const int tid  = threadIdx.x;
  const int lane = tid & 63;
  const int lo   = lane & 15;
  const int hi   = lane >> 4;
  const int wid  = tid >> 6;
  const int wm   = wid >> 2;       // 0..1
  const int wn   = wid & 3;        // 0..3
  const int D  = blockIdx.x;
  const int h  = D & 7;
  const int r_ = D >> 3;
  const int p  = r_ >> 2;
  const int n  = r_ & 3;

  const unsigned short* slab = ekb + ((size_t)h*1024 + n*256) * SEQ;

  #pragma unroll
  for (int half = 0; half < 2; ++half){
    const int tt = half ? p : (15 - p);
    const int t0 = tt * 128;
    const int nst = 2*tt + 2;
    const unsigned short* abase = ewb + ((size_t)h*SEQ + t0) * SEQ;

    f32x4 acc[4][4] = {};

    auto stage_unit = [&](int st, int slot, int u){
      const int s0 = st * 64;
      const int po = tid * 16;
      const int r  = po >> 7;
      const int k2 = (po & 127) ^ ((r & 7) << 4);
      if (u < 2){
        unsigned short* lb = Asl + slot*(128*64) + u*(64*64);
        gld_lds16(abase + (size_t)(u*64 + r)*SEQ + s0 + (k2 >> 1), (char*)lb + po);
      } else {
        unsigned short* lb = Bsl + slot*(256*64) + (u-2)*(64*64);
        gld_lds16(slab + (size_t)((u-2)*64 + r)*SEQ + s0 + (k2 >> 1), (char*)lb + po);
      }
    };

    #pragma unroll
    for (int u = 0; u < 6; ++u) stage_unit(0, 0, u);

    for (int t = 0; t < nst; ++t){
      const int s = t & 1;
      const char* Ab = (const char*)(Asl + s*(128*64));
      const char* Bb = (const char*)(Bsl + s*(256*64));
      #pragma unroll
      for (int q = 0; q < 4; ++q){
        if (q < 3 && t + 1 < nst){
          stage_unit(t + 1, s ^ 1, q*2);
          stage_unit(t + 1, s ^ 1, q*2 + 1);
        }
        if (q == 0){
          if (t + 1 < nst) { VMCNT(2); } else { VMCNT(0); }
        }
        SCHED0();
        SBAR();
        SCHED0();
        bf16x8 a[2], b[4][2];
        {
          const int R = wm*64 + q*16 + lo;
          #pragma unroll
          for (int ks = 0; ks < 2; ++ks){
            const int K2 = (ks*64 + hi*16) ^ ((R & 7) << 4);
            a[ks] = *reinterpret_cast<const bf16x8*>(Ab + R*128 + K2);
          }
        }
        #pragma unroll
        for (int nf = 0; nf < 4; ++nf){
          const int R = wn*64 + nf*16 + lo;
          #pragma unroll
          for (int ks = 0; ks < 2; ++ks){
            const int K2 = (ks*64 + hi*16) ^ ((R & 7) << 4);
            b[nf][ks] = *reinterpret_cast<const bf16x8*>(Bb + R*128 + K2);
          }
        }
        __builtin_amdgcn_s_setprio(1);
        #pragma unroll
        for (int ks = 0; ks < 2; ++ks)
          #pragma unroll
          for (int nf = 0; nf < 4; ++nf)
            acc[q][nf] = __builtin_amdgcn_mfma_f32_16x16x32_bf16(
                a[ks], b[nf][ks], acc[q][nf], 0, 0, 0);
        __builtin_amdgcn_s_setprio(0);
        SCHED0();
        SBAR();
      }
    }

    // ---- fused division epilogue ----
    __syncthreads();
    if (wn >= 2){
      #pragma unroll
      for (int mf = 0; mf < 4; ++mf){
        const int rloc = wm*64 + mf*16 + hi*4;
        #pragma unroll
        for (int nf = 0; nf < 4; ++nf){
          const int dv = (wn - 2)*64 + nf*16 + lo;     // num col 0..127
          #pragma unroll
          for (int jj = 0; jj < 4; ++jj)
            xch[(size_t)(rloc + jj)*129 + dv] = acc[mf][nf][jj];
        }
      }
    }
    __syncthreads();
    if (wn < 2){
      #pragma unroll
      for (int nf = 0; nf < 4; ++nf){
        const int d = wn*64 + nf*16 + lo;              // den col 0..127
        #pragma unroll
        for (int mf = 0; mf < 4; ++mf){
          const int rloc = wm*64 + mf*16 + hi*4;
          #pragma unroll
          for (int jj = 0; jj < 4; ++jj){
            const int t = t0 + rloc + jj;
            const float num = xch[(size_t)(rloc + jj)*129 + d];
            aftb[((size_t)n*SEQ + t)*DIM + h*HD + d] = f2bf(num / acc[mf][nf][jj]);
          }
        }
      }
    }
    __syncthreads();   // xch reads done before next half's staging reuses smem
  }
}

// ---------------- output projection: 8-phase, BM=128 BN=256 (R9/R11, proven) ----------------
__global__ __launch_bounds__(512) void k_out(
    const unsigned short* __restrict__ aftb,
    const unsigned short* __restrict__ wot,
    const float* __restrict__ bo,
    float* __restrict__ out)
{
  __shared__ __align__(16) char smem[98304];
  unsigned short* Asl = (unsigned short*)smem;            // [2][128*64]
  unsigned short* Bsl = (unsigned short*)(smem + 32768);  // [2][256*64]

  const int tid  = threadIdx.x;
  const int lane = tid & 63;
  const int lo   = lane & 15;
  const int hi   = lane >> 4;
  const int wid  = tid >> 6;
  const int wm   = wid >> 2;
  const int wn   = wid & 3;
  const int D    = blockIdx.x;
  const int row0 = (D >> 2) * 128;
  const int col0 = (D & 3) * 256;

  f32x4 acc[4][4] = {};

  auto stage_unit = [&](int kt, int slot, int u){
    const int po = tid * 16;
    const int r  = po >> 7;
    const int k2 = (po & 127) ^ ((r & 7) << 4);
    if (u < 2){
      unsigned short* lb = Asl + slot*(128*64) + u*(64*64);
      gld_lds16(aftb + (size_t)(row0 + u*64 + r)*DIM + kt*64 + (k2 >> 1), (char*)lb + po);
    } else {
      unsigned short* lb = Bsl + slot*(256*64) + (u-2)*(64*64);
      gld_lds16(wot + (size_t)(col0 + (u-2)*64 + r)*DIM + kt*64 + (k2 >> 1), (char*)lb + po);
    }
  };

  #pragma unroll
  for (int u = 0; u < 6; ++u) stage_unit(0, 0, u);

  for (int t = 0; t < 16; ++t){
    const int s = t & 1;
    const char* Ab = (const char*)(Asl + s*(128*64));
    const char* Bb = (const char*)(Bsl + s*(256*64));
    #pragma unroll
    for (int q = 0; q < 4; ++q){
      if (q < 3 && t + 1 < 16){
        stage_unit(t + 1, s ^ 1, q*2);
        stage_unit(t + 1, s ^ 1, q*2 + 1);
      }
      if (q == 0){
        if (t + 1 < 16) { VMCNT(2); } else { VMCNT(0); }
      }
      SCHED0();
      SBAR();
      SCHED0();
      bf16x8 a[2], b[4][2];
      {
        const int R = wm*64 + q*16 + lo;
        #pragma unroll
        for (int ks = 0; ks < 2; ++ks){
          const int K2 = (ks*64 + hi*16) ^ ((R & 7) << 4);
          a[ks] = *reinterpret_cast<const bf16x8*>(Ab + R*128 + K2);
        }
      }
      #pragma unroll
      for (int nf = 0; nf < 4; ++nf){
        const int R = wn*64 + nf*16 + lo;
        #pragma unroll
        for (int ks = 0; ks < 2; ++ks){
          const int K2 = (ks*64 + hi*16) ^ ((R & 7) << 4);
          b[nf][ks] = *reinterpret_cast<const bf16x8*>(Bb + R*128 + K2);
        }
      }
      __builtin_amdgcn_s_setprio(1);
      #pragma unroll
      for (int ks = 0; ks < 2; ++ks)
        #pragma unroll
        for (int nf = 0; nf < 4; ++nf)
          acc[q][nf] = __builtin_amdgcn_mfma_f32_16x16x32_bf16(
              a[ks], b[nf][ks], acc[q][nf], 0, 0, 0);
      __builtin_amdgcn_s_setprio(0);
      SCHED0();
      SBAR();
    }
  }

  #pragma unroll
  for (int nf = 0; nf < 4; ++nf){
    const int c = col0 + wn*64 + nf*16 + lo;
    const float boc = bo[c];
    #pragma unroll
    for (int mf = 0; mf < 4; ++mf){
      #pragma unroll
      for (int jj = 0; jj < 4; ++jj){
        const int r = row0 + wm*64 + mf*16 + hi*4 + jj;
        out[(size_t)r*DIM + c] = acc[mf][nf][jj] + boc;
      }
    }
  }
}

extern "C" void kernel_launch(void* const* d_in, const int* in_sizes, int n_in,
                              void* d_out, int out_size, void* d_ws, size_t ws_size,
                              hipStream_t stream){
  const float* x    = (const float*)d_in[0];
  const float* Wk   = (const float*)d_in[1];
  const float* bk   = (const float*)d_in[2];
  const float* Wv   = (const float*)d_in[3];
  const float* bv   = (const float*)d_in[4];
  const float* waft = (const float*)d_in[5];
  const float* Wo   = (const float*)d_in[6];
  const float* bo   = (const float*)d_in[7];
  float* out = (float*)d_out;

  char* w = (char*)d_ws;
  unsigned short* xb   = (unsigned short*)w; w += (size_t)ROWS*DIM*2;       // 16 MB
  unsigned short* wkt  = (unsigned short*)w; w += (size_t)DIM*DIM*2;        // 2 MB
  unsigned short* wvt  = (unsigned short*)w; w += (size_t)DIM*DIM*2;        // 2 MB
  unsigned short* wot  = (unsigned short*)w; w += (size_t)DIM*DIM*2;        // 2 MB
  unsigned short* ekb  = (unsigned short*)w; w += (size_t)HEADS*1024*SEQ*2; // 32 MB
  unsigned short* aftb = (unsigned short*)w; w += (size_t)ROWS*DIM*2;       // 16 MB
  unsigned short* ewb  = (unsigned short*)w; w += (size_t)HEADS*SEQ*SEQ*2;  // 64 MB

  k_prep0<<<2816, 256, 0, stream>>>(x, Wk, Wv, Wo, xb, wkt, wvt, wot);
  k_projew<<<512, 512, 0, stream>>>(xb, wkt, wvt, bk, bv, waft, ekb, ewb);
  k_core<<<256, 512, 0, stream>>>(ewb, ekb, aftb);
  k_out<<<256, 512, 0, stream>>>(aftb, wot, bo, out);
}

// Round 13
// 169.950 us; speedup vs baseline: 1.1866x; 1.1866x over previous
//
#include <hip/hip_runtime.h>
#include <hip/hip_bf16.h>
#include <stdint.h>

#define DIM 1024
#define SEQ 2048
#define NB 4
#define HEADS 8
#define HD 128
#define ROWS (NB*SEQ)   // 8192

typedef __attribute__((ext_vector_type(8))) short bf16x8;
typedef __attribute__((ext_vector_type(4))) float f32x4;

#define VMCNT(n) asm volatile("s_waitcnt vmcnt(" #n ")" ::: "memory")
#define LGKM0()  asm volatile("s_waitcnt lgkmcnt(0)" ::: "memory")
#define SBAR()   __builtin_amdgcn_s_barrier()
#define SCHED0() __builtin_amdgcn_sched_barrier(0)

static __device__ __forceinline__ unsigned short f2bf(float f){
  union { float f; unsigned int u; } x; x.f = f;
  unsigned int r = x.u + 0x7fffu + ((x.u >> 16) & 1u);
  return (unsigned short)(r >> 16);
}

static __device__ __forceinline__ void gld_lds16(const void* g, void* l){
  __builtin_amdgcn_global_load_lds(
      (const __attribute__((address_space(1))) void*)g,
      (__attribute__((address_space(3))) void*)l,
      16, 0, 0);
}

// ---------------- prep: transpose 3 weights | exp(w_aft) (cast pass eliminated) ----------
// blocks [0,768): transpose; [768,17152): ew (t=D&2047, h=D>>11).
__global__ void k_prep(const float* __restrict__ Wk, const float* __restrict__ Wv,
                       const float* __restrict__ Wo, const float* __restrict__ waft,
                       unsigned short* __restrict__ Tk, unsigned short* __restrict__ Tv,
                       unsigned short* __restrict__ To, unsigned short* __restrict__ ewb){
  __shared__ float tile[64][65];
  const int B = blockIdx.x;
  const int tid = threadIdx.x;
  if (B < 768){
    const int z = B >> 8;
    const int rem = B & 255;
    const int bo = (rem & 15) * 64;
    const int bi = (rem >> 4) * 64;
    const float* W = (z == 0) ? Wk : (z == 1) ? Wv : Wo;
    unsigned short* WT = (z == 0) ? Tk : (z == 1) ? Tv : To;
    #pragma unroll
    for (int it = 0; it < 16; ++it){
      int f = it*256 + tid;
      int r = f >> 6, c = f & 63;
      tile[r][c] = W[(size_t)(bi + r) * DIM + bo + c];
    }
    __syncthreads();
    #pragma unroll
    for (int it = 0; it < 16; ++it){
      int f = it*256 + tid;
      int r = f >> 6, c = f & 63;
      WT[(size_t)(bo + r) * DIM + bi + c] = f2bf(tile[c][r]);
    }
  } else {
    const int D = B - 768;
    const int t = D & 2047;
    const int h = D >> 11;
    const float* src = waft + ((size_t)h*SEQ + t) * SEQ;
    unsigned short* dst = ewb + ((size_t)h*SEQ + t) * SEQ;
    const int smax4 = ((t & ~127) + 128) >> 2;
    for (int i = tid; i < smax4; i += 256){
      const float4 w4 = reinterpret_cast<const float4*>(src)[i];
      const int s = i * 4;
      ushort4 o;
      o.x = (s+0 <= t) ? f2bf(__expf(w4.x)) : (unsigned short)0;
      o.y = (s+1 <= t) ? f2bf(__expf(w4.y)) : (unsigned short)0;
      o.z = (s+2 <= t) ? f2bf(__expf(w4.z)) : (unsigned short)0;
      o.w = (s+3 <= t) ? f2bf(__expf(w4.w)) : (unsigned short)0;
      reinterpret_cast<ushort4*>(dst)[i] = o;
    }
  }
}

// ---------------- fused K/V projection: 8-phase 256^2, A reg-staged from f32 x ----------------
// Grid 256, 512 thr (8 waves 2Mx4N). A (x rows) read as f32 + f2bf in-kernel (cast pass
// eliminated). Per tile t (for t+1): q0 issue A-h0 4xfloat4; q1 issue A-h1; q2 gld_lds B.k;
// q3 gld_lds B.v + VMCNT(4) [drains A8, leaves B4 in flight] + f2bf + 4x ds_write_b128 +
// lgkmcnt(0). q0 VMCNT(4) drains prev tile's B4. Never vmcnt(0) mid-loop (T4).
__global__ __launch_bounds__(512) void k_proj(
    const float* __restrict__ xf,
    const unsigned short* __restrict__ wkt,
    const unsigned short* __restrict__ wvt,
    const float* __restrict__ bk,
    const float* __restrict__ bv,
    unsigned short* __restrict__ ekb)
{
  __shared__ __align__(16) char smem[131072];
  unsigned short* Asl = (unsigned short*)smem;            // [2][256*64]
  unsigned short* Bsl = (unsigned short*)(smem + 65536);  // [2][256*64]
  float* xch = (float*)smem;                              // epilogue scratch [256][128]

  const int tid  = threadIdx.x;
  const int lane = tid & 63;
  const int lo   = lane & 15;
  const int hi   = lane >> 4;
  const int wid  = tid >> 6;
  const int wm   = wid >> 2;
  const int wn   = wid & 3;
  const int D    = blockIdx.x;
  const int row0 = (D >> 3) * 256;
  const int col0k = (D & 7) * 128;

  f32x4 acc[8][4] = {};
  float4 rA[2][2][2];   // [half][it][lo/hi float4]

  auto issueA = [&](int kt, int half){
    #pragma unroll
    for (int it = 0; it < 2; ++it){
      const int po = (it*512 + tid)*16;
      const int r  = po >> 7;
      const int k2 = (po & 127) ^ ((r & 7) << 4);
      const float* src = xf + (size_t)(row0 + half*128 + r)*DIM + kt*64 + (k2 >> 1);
      rA[half][it][0] = *reinterpret_cast<const float4*>(src);
      rA[half][it][1] = *reinterpret_cast<const float4*>(src + 4);
    }
  };
  auto writeA = [&](int slot){
    #pragma unroll
    for (int half = 0; half < 2; ++half)
      #pragma unroll
      for (int it = 0; it < 2; ++it){
        const int po = (it*512 + tid)*16;
        bf16x8 pk;
        const float* f0 = (const float*)&rA[half][it][0];
        #pragma unroll
        for (int j = 0; j < 4; ++j) ((unsigned short*)&pk)[j] = f2bf(f0[j]);
        const float* f1 = (const float*)&rA[half][it][1];
        #pragma unroll
        for (int j = 0; j < 4; ++j) ((unsigned short*)&pk)[4+j] = f2bf(f1[j]);
        *reinterpret_cast<bf16x8*>((char*)Asl + slot*32768 + half*16384 + po) = pk;
      }
  };
  auto stageB = [&](int kt, int slot, int v){
    unsigned short* lb = Bsl + slot*(256*64) + v*(128*64);
    const unsigned short* gb = (v == 0 ? wkt : wvt) + (size_t)col0k*DIM + kt*64;
    #pragma unroll
    for (int it = 0; it < 2; ++it){
      const int po = (it*512 + tid)*16;
      const int r  = po >> 7;
      const int k2 = (po & 127) ^ ((r & 7) << 4);
      gld_lds16(gb + (size_t)r*DIM + (k2 >> 1), (char*)lb + po);
    }
  };

  // prologue: tile 0 into slot 0
  issueA(0, 0); issueA(0, 1);      // 8 f32x4 in flight
  stageB(0, 0, 0); stageB(0, 0, 1); // +4 gld_lds
  VMCNT(4);                         // A landed, B4 in flight
  SCHED0();
  writeA(0);
  LGKM0();
  SCHED0();

  for (int t = 0; t < 16; ++t){
    const int s = t & 1;
    const bool nxt = (t + 1 < 16);
    const char* Ab = (const char*)Asl + s*32768;
    const char* Bb = (const char*)Bsl + s*32768;
    #pragma unroll
    for (int q = 0; q < 4; ++q){
      if (q == 0){
        if (nxt){ issueA(t + 1, 0); VMCNT(4); } else { VMCNT(0); }
      } else if (q == 1){
        if (nxt) issueA(t + 1, 1);
      } else if (q == 2){
        if (nxt) stageB(t + 1, s ^ 1, 0);
      } else {
        if (nxt){
          stageB(t + 1, s ^ 1, 1);
          VMCNT(4);                 // A8 landed; B4 (t+1) in flight
          SCHED0();
          writeA(s ^ 1);
          LGKM0();
        }
      }
      SCHED0();
      SBAR();
      SCHED0();
      bf16x8 a[2][2], b[4][2];
      #pragma unroll
      for (int mf = 0; mf < 2; ++mf){
        const int R = wm*128 + (q*2 + mf)*16 + lo;
        #pragma unroll
        for (int ks = 0; ks < 2; ++ks){
          const int K2 = (ks*64 + hi*16) ^ ((R & 7) << 4);
          a[mf][ks] = *reinterpret_cast<const bf16x8*>(Ab + R*128 + K2);
        }
      }
      #pragma unroll
      for (int nf = 0; nf < 4; ++nf){
        const int R = wn*64 + nf*16 + lo;
        #pragma unroll
        for (int ks = 0; ks < 2; ++ks){
          const int K2 = (ks*64 + hi*16) ^ ((R & 7) << 4);
          b[nf][ks] = *reinterpret_cast<const bf16x8*>(Bb + R*128 + K2);
        }
      }
      __builtin_amdgcn_s_setprio(1);
      #pragma unroll
      for (int ks = 0; ks < 2; ++ks)
        #pragma unroll
        for (int mf = 0; mf < 2; ++mf)
          #pragma unroll
          for (int nf = 0; nf < 4; ++nf)
            acc[q*2+mf][nf] = __builtin_amdgcn_mfma_f32_16x16x32_bf16(
                a[mf][ks], b[nf][ks], acc[q*2+mf][nf], 0, 0, 0);
      __builtin_amdgcn_s_setprio(0);
      SCHED0();
      SBAR();
    }
  }

  __syncthreads();
  if (wn >= 2){
    #pragma unroll
    for (int mf = 0; mf < 8; ++mf){
      const int rloc = wm*128 + mf*16 + hi*4;
      #pragma unroll
      for (int nf = 0; nf < 4; ++nf){
        const int cv = (wn - 2)*64 + nf*16 + lo;
        #pragma unroll
        for (int jj = 0; jj < 4; ++jj)
          xch[(size_t)(rloc + jj)*128 + cv] = acc[mf][nf][jj];
      }
    }
  }
  __syncthreads();
  if (wn < 2){
    #pragma unroll
    for (int nf = 0; nf < 4; ++nf){
      const int ck = wn*64 + nf*16 + lo;
      const int c  = col0k + ck;
      const int h  = c >> 7;
      const int d  = c & 127;
      const float bkc = bk[c];
      const float bvc = bv[c];
      #pragma unroll
      for (int mf = 0; mf < 8; ++mf){
        const int rloc = wm*128 + mf*16 + hi*4;
        const int r = row0 + rloc;
        const int n = r >> 11;
        const int sidx = r & 2047;
        ushort4 pk, pv;
        #pragma unroll
        for (int jj = 0; jj < 4; ++jj){
          const float kval = acc[mf][nf][jj] + bkc;
          const float vval = xch[(size_t)(rloc + jj)*128 + ck] + bvc;
          const float ek = __expf(kval);
          ((unsigned short*)&pk)[jj] = f2bf(ek);
          ((unsigned short*)&pv)[jj] = f2bf(ek * vval);
        }
        const size_t idx = ((size_t)h*1024 + n*256 + d) * SEQ + sidx;
        *reinterpret_cast<ushort4*>(&ekb[idx]) = pk;
        *reinterpret_cast<ushort4*>(&ekb[idx + (size_t)128*SEQ]) = pv;
      }
    }
  }
}

// ---------------- AFT causal core: 8-phase, BM=128 BN=256 (den|num), fused division ----------
// (R9/R11 proven version: uniform 34 K-steps/block via triangle pairing {15-p, p})
__global__ __launch_bounds__(512) void k_core(
    const unsigned short* __restrict__ ewb,
    const unsigned short* __restrict__ ekb,
    unsigned short* __restrict__ aftb)
{
  __shared__ __align__(16) char smem[98304];              // A[2][128*64] + B[2][256*64]
  unsigned short* Asl = (unsigned short*)smem;            // 32 KB
  unsigned short* Bsl = (unsigned short*)(smem + 32768);  // 64 KB
  float* xch = (float*)smem;                              // epilogue [128][129] f32

  const int tid  = threadIdx.x;
  const int lane = tid & 63;
  const int lo   = lane & 15;
  const int hi   = lane >> 4;
  const int wid  = tid >> 6;
  const int wm   = wid >> 2;       // 0..1
  const int wn   = wid & 3;        // 0..3
  const int D  = blockIdx.x;
  const int h  = D & 7;
  const int r_ = D >> 3;
  const int p  = r_ >> 2;
  const int n  = r_ & 3;

  const unsigned short* slab = ekb + ((size_t)h*1024 + n*256) * SEQ;

  #pragma unroll
  for (int half = 0; half < 2; ++half){
    const int tt = half ? p : (15 - p);
    const int t0 = tt * 128;
    const int nst = 2*tt + 2;
    const unsigned short* abase = ewb + ((size_t)h*SEQ + t0) * SEQ;

    f32x4 acc[4][4] = {};

    auto stage_unit = [&](int st, int slot, int u){
      const int s0 = st * 64;
      const int po = tid * 16;
      const int r  = po >> 7;
      const int k2 = (po & 127) ^ ((r & 7) << 4);
      if (u < 2){
        unsigned short* lb = Asl + slot*(128*64) + u*(64*64);
        gld_lds16(abase + (size_t)(u*64 + r)*SEQ + s0 + (k2 >> 1), (char*)lb + po);
      } else {
        unsigned short* lb = Bsl + slot*(256*64) + (u-2)*(64*64);
        gld_lds16(slab + (size_t)((u-2)*64 + r)*SEQ + s0 + (k2 >> 1), (char*)lb + po);
      }
    };

    #pragma unroll
    for (int u = 0; u < 6; ++u) stage_unit(0, 0, u);

    for (int t = 0; t < nst; ++t){
      const int s = t & 1;
      const char* Ab = (const char*)(Asl + s*(128*64));
      const char* Bb = (const char*)(Bsl + s*(256*64));
      #pragma unroll
      for (int q = 0; q < 4; ++q){
        if (q < 3 && t + 1 < nst){
          stage_unit(t + 1, s ^ 1, q*2);
          stage_unit(t + 1, s ^ 1, q*2 + 1);
        }
        if (q == 0){
          if (t + 1 < nst) { VMCNT(2); } else { VMCNT(0); }
        }
        SCHED0();
        SBAR();
        SCHED0();
        bf16x8 a[2], b[4][2];
        {
          const int R = wm*64 + q*16 + lo;
          #pragma unroll
          for (int ks = 0; ks < 2; ++ks){
            const int K2 = (ks*64 + hi*16) ^ ((R & 7) << 4);
            a[ks] = *reinterpret_cast<const bf16x8*>(Ab + R*128 + K2);
          }
        }
        #pragma unroll
        for (int nf = 0; nf < 4; ++nf){
          const int R = wn*64 + nf*16 + lo;
          #pragma unroll
          for (int ks = 0; ks < 2; ++ks){
            const int K2 = (ks*64 + hi*16) ^ ((R & 7) << 4);
            b[nf][ks] = *reinterpret_cast<const bf16x8*>(Bb + R*128 + K2);
          }
        }
        __builtin_amdgcn_s_setprio(1);
        #pragma unroll
        for (int ks = 0; ks < 2; ++ks)
          #pragma unroll
          for (int nf = 0; nf < 4; ++nf)
            acc[q][nf] = __builtin_amdgcn_mfma_f32_16x16x32_bf16(
                a[ks], b[nf][ks], acc[q][nf], 0, 0, 0);
        __builtin_amdgcn_s_setprio(0);
        SCHED0();
        SBAR();
      }
    }

    // ---- fused division epilogue ----
    __syncthreads();
    if (wn >= 2){
      #pragma unroll
      for (int mf = 0; mf < 4; ++mf){
        const int rloc = wm*64 + mf*16 + hi*4;
        #pragma unroll
        for (int nf = 0; nf < 4; ++nf){
          const int dv = (wn - 2)*64 + nf*16 + lo;     // num col 0..127
          #pragma unroll
          for (int jj = 0; jj < 4; ++jj)
            xch[(size_t)(rloc + jj)*129 + dv] = acc[mf][nf][jj];
        }
      }
    }
    __syncthreads();
    if (wn < 2){
      #pragma unroll
      for (int nf = 0; nf < 4; ++nf){
        const int d = wn*64 + nf*16 + lo;              // den col 0..127
        #pragma unroll
        for (int mf = 0; mf < 4; ++mf){
          const int rloc = wm*64 + mf*16 + hi*4;
          #pragma unroll
          for (int jj = 0; jj < 4; ++jj){
            const int t = t0 + rloc + jj;
            const float num = xch[(size_t)(rloc + jj)*129 + d];
            aftb[((size_t)n*SEQ + t)*DIM + h*HD + d] = f2bf(num / acc[mf][nf][jj]);
          }
        }
      }
    }
    __syncthreads();   // xch reads done before next half's staging reuses smem
  }
}

// ---------------- output projection: 8-phase, BM=128 BN=256 (R9/R11, proven) ----------------
__global__ __launch_bounds__(512) void k_out(
    const unsigned short* __restrict__ aftb,
    const unsigned short* __restrict__ wot,
    const float* __restrict__ bo,
    float* __restrict__ out)
{
  __shared__ __align__(16) char smem[98304];
  unsigned short* Asl = (unsigned short*)smem;            // [2][128*64]
  unsigned short* Bsl = (unsigned short*)(smem + 32768);  // [2][256*64]

  const int tid  = threadIdx.x;
  const int lane = tid & 63;
  const int lo   = lane & 15;
  const int hi   = lane >> 4;
  const int wid  = tid >> 6;
  const int wm   = wid >> 2;
  const int wn   = wid & 3;
  const int D    = blockIdx.x;
  const int row0 = (D >> 2) * 128;
  const int col0 = (D & 3) * 256;

  f32x4 acc[4][4] = {};

  auto stage_unit = [&](int kt, int slot, int u){
    const int po = tid * 16;
    const int r  = po >> 7;
    const int k2 = (po & 127) ^ ((r & 7) << 4);
    if (u < 2){
      unsigned short* lb = Asl + slot*(128*64) + u*(64*64);
      gld_lds16(aftb + (size_t)(row0 + u*64 + r)*DIM + kt*64 + (k2 >> 1), (char*)lb + po);
    } else {
      unsigned short* lb = Bsl + slot*(256*64) + (u-2)*(64*64);
      gld_lds16(wot + (size_t)(col0 + (u-2)*64 + r)*DIM + kt*64 + (k2 >> 1), (char*)lb + po);
    }
  };

  #pragma unroll
  for (int u = 0; u < 6; ++u) stage_unit(0, 0, u);

  for (int t = 0; t < 16; ++t){
    const int s = t & 1;
    const char* Ab = (const char*)(Asl + s*(128*64));
    const char* Bb = (const char*)(Bsl + s*(256*64));
    #pragma unroll
    for (int q = 0; q < 4; ++q){
      if (q < 3 && t + 1 < 16){
        stage_unit(t + 1, s ^ 1, q*2);
        stage_unit(t + 1, s ^ 1, q*2 + 1);
      }
      if (q == 0){
        if (t + 1 < 16) { VMCNT(2); } else { VMCNT(0); }
      }
      SCHED0();
      SBAR();
      SCHED0();
      bf16x8 a[2], b[4][2];
      {
        const int R = wm*64 + q*16 + lo;
        #pragma unroll
        for (int ks = 0; ks < 2; ++ks){
          const int K2 = (ks*64 + hi*16) ^ ((R & 7) << 4);
          a[ks] = *reinterpret_cast<const bf16x8*>(Ab + R*128 + K2);
        }
      }
      #pragma unroll
      for (int nf = 0; nf < 4; ++nf){
        const int R = wn*64 + nf*16 + lo;
        #pragma unroll
        for (int ks = 0; ks < 2; ++ks){
          const int K2 = (ks*64 + hi*16) ^ ((R & 7) << 4);
          b[nf][ks] = *reinterpret_cast<const bf16x8*>(Bb + R*128 + K2);
        }
      }
      __builtin_amdgcn_s_setprio(1);
      #pragma unroll
      for (int ks = 0; ks < 2; ++ks)
        #pragma unroll
        for (int nf = 0; nf < 4; ++nf)
          acc[q][nf] = __builtin_amdgcn_mfma_f32_16x16x32_bf16(
              a[ks], b[nf][ks], acc[q][nf], 0, 0, 0);
      __builtin_amdgcn_s_setprio(0);
      SCHED0();
      SBAR();
    }
  }

  #pragma unroll
  for (int nf = 0; nf < 4; ++nf){
    const int c = col0 + wn*64 + nf*16 + lo;
    const float boc = bo[c];
    #pragma unroll
    for (int mf = 0; mf < 4; ++mf){
      #pragma unroll
      for (int jj = 0; jj < 4; ++jj){
        const int r = row0 + wm*64 + mf*16 + hi*4 + jj;
        out[(size_t)r*DIM + c] = acc[mf][nf][jj] + boc;
      }
    }
  }
}

extern "C" void kernel_launch(void* const* d_in, const int* in_sizes, int n_in,
                              void* d_out, int out_size, void* d_ws, size_t ws_size,
                              hipStream_t stream){
  const float* x    = (const float*)d_in[0];
  const float* Wk   = (const float*)d_in[1];
  const float* bk   = (const float*)d_in[2];
  const float* Wv   = (const float*)d_in[3];
  const float* bv   = (const float*)d_in[4];
  const float* waft = (const float*)d_in[5];
  const float* Wo   = (const float*)d_in[6];
  const float* bo   = (const float*)d_in[7];
  float* out = (float*)d_out;

  char* w = (char*)d_ws;
  unsigned short* wkt  = (unsigned short*)w; w += (size_t)DIM*DIM*2;        // 2 MB
  unsigned short* wvt  = (unsigned short*)w; w += (size_t)DIM*DIM*2;        // 2 MB
  unsigned short* wot  = (unsigned short*)w; w += (size_t)DIM*DIM*2;        // 2 MB
  unsigned short* ekb  = (unsigned short*)w; w += (size_t)HEADS*1024*SEQ*2; // 32 MB
  unsigned short* aftb = (unsigned short*)w; w += (size_t)ROWS*DIM*2;       // 16 MB
  unsigned short* ewb  = (unsigned short*)w; w += (size_t)HEADS*SEQ*SEQ*2;  // 64 MB

  k_prep<<<17152, 256, 0, stream>>>(Wk, Wv, Wo, waft, wkt, wvt, wot, ewb);
  k_proj<<<256, 512, 0, stream>>>(x, wkt, wvt, bk, bv, ekb);
  k_core<<<256, 512, 0, stream>>>(ewb, ekb, aftb);
  k_out<<<256, 512, 0, stream>>>(aftb, wot, bo, out);
}

// Round 14
// 160.351 us; speedup vs baseline: 1.2576x; 1.0599x over previous
//
#include <hip/hip_runtime.h>
#include <hip/hip_bf16.h>
#include <stdint.h>

#define DIM 1024
#define SEQ 2048
#define NB 4
#define HEADS 8
#define HD 128
#define ROWS (NB*SEQ)   // 8192

typedef __attribute__((ext_vector_type(8))) short bf16x8;
typedef __attribute__((ext_vector_type(4))) float f32x4;

#define VMCNT(n) asm volatile("s_waitcnt vmcnt(" #n ")" ::: "memory")
#define SBAR()   __builtin_amdgcn_s_barrier()
#define SCHED0() __builtin_amdgcn_sched_barrier(0)

static __device__ __forceinline__ unsigned short f2bf(float f){
  union { float f; unsigned int u; } x; x.f = f;
  unsigned int r = x.u + 0x7fffu + ((x.u >> 16) & 1u);
  return (unsigned short)(r >> 16);
}

static __device__ __forceinline__ void gld_lds16(const void* g, void* l){
  __builtin_amdgcn_global_load_lds(
      (const __attribute__((address_space(1))) void*)g,
      (__attribute__((address_space(3))) void*)l,
      16, 0, 0);
}

// ---------------- merged prep: cast x | transpose 3 weights | exp(w_aft) per-wave ----------
// blocks [0,2048): cast; [2048,2816): transpose; [2816,6912): ew, one row per WAVE
// (4 rows/block, lane-strided) — worst-case lane util 32/64 vs old 32/256.
__global__ void k_prep(const float* __restrict__ x,
                       const float* __restrict__ Wk, const float* __restrict__ Wv,
                       const float* __restrict__ Wo, const float* __restrict__ waft,
                       unsigned short* __restrict__ xb,
                       unsigned short* __restrict__ Tk, unsigned short* __restrict__ Tv,
                       unsigned short* __restrict__ To, unsigned short* __restrict__ ewb){
  __shared__ float tile[64][65];
  const int B = blockIdx.x;
  const int tid = threadIdx.x;
  if (B < 2048){
    for (int i = B*256 + tid; i < ROWS*DIM/4; i += 2048*256){
      const float4 v = reinterpret_cast<const float4*>(x)[i];
      ushort4 o;
      o.x = f2bf(v.x); o.y = f2bf(v.y); o.z = f2bf(v.z); o.w = f2bf(v.w);
      reinterpret_cast<ushort4*>(xb)[i] = o;
    }
  } else if (B < 2816){
    const int D = B - 2048;
    const int z = D >> 8;
    const int rem = D & 255;
    const int bo = (rem & 15) * 64;
    const int bi = (rem >> 4) * 64;
    const float* W = (z == 0) ? Wk : (z == 1) ? Wv : Wo;
    unsigned short* WT = (z == 0) ? Tk : (z == 1) ? Tv : To;
    #pragma unroll
    for (int it = 0; it < 16; ++it){
      int f = it*256 + tid;
      int r = f >> 6, c = f & 63;
      tile[r][c] = W[(size_t)(bi + r) * DIM + bo + c];
    }
    __syncthreads();
    #pragma unroll
    for (int it = 0; it < 16; ++it){
      int f = it*256 + tid;
      int r = f >> 6, c = f & 63;
      WT[(size_t)(bo + r) * DIM + bi + c] = f2bf(tile[c][r]);
    }
  } else {
    const int row = (B - 2816) * 4 + (tid >> 6);
    const int lane = tid & 63;
    const int t = row & 2047;
    const int h = row >> 11;
    const float* src = waft + ((size_t)h*SEQ + t) * SEQ;
    unsigned short* dst = ewb + ((size_t)h*SEQ + t) * SEQ;
    const int smax4 = ((t & ~127) + 128) >> 2;
    for (int i = lane; i < smax4; i += 64){
      const float4 w4 = reinterpret_cast<const float4*>(src)[i];
      const int s = i * 4;
      ushort4 o;
      o.x = (s+0 <= t) ? f2bf(__expf(w4.x)) : (unsigned short)0;
      o.y = (s+1 <= t) ? f2bf(__expf(w4.y)) : (unsigned short)0;
      o.z = (s+2 <= t) ? f2bf(__expf(w4.z)) : (unsigned short)0;
      o.w = (s+3 <= t) ? f2bf(__expf(w4.w)) : (unsigned short)0;
      reinterpret_cast<ushort4*>(dst)[i] = o;
    }
  }
}

// ---------------- fused K/V projection: 8-phase 256^2 schedule (R8/R9/R11, proven) ----------------
__global__ __launch_bounds__(512) void k_proj(
    const unsigned short* __restrict__ xb,
    const unsigned short* __restrict__ wkt,
    const unsigned short* __restrict__ wvt,
    const float* __restrict__ bk,
    const float* __restrict__ bv,
    unsigned short* __restrict__ ekb)
{
  __shared__ __align__(16) char smem[131072];
  unsigned short* Asl = (unsigned short*)smem;            // [2][256*64]
  unsigned short* Bsl = (unsigned short*)(smem + 65536);  // [2][256*64]
  float* xch = (float*)smem;                              // epilogue scratch [256][128]

  const int tid  = threadIdx.x;
  const int lane = tid & 63;
  const int lo   = lane & 15;
  const int hi   = lane >> 4;
  const int wid  = tid >> 6;
  const int wm   = wid >> 2;
  const int wn   = wid & 3;
  const int D    = blockIdx.x;
  const int mb   = D >> 3;
  const int cb   = D & 7;
  const int row0 = mb * 256;
  const int col0k = cb * 128;

  f32x4 acc[8][4] = {};

  auto stage_unit = [&](int kt, int slot, int u){
    const int half = u & 1;
    const bool isB = (u >> 1) != 0;
    unsigned short* lb = (isB ? Bsl : Asl) + slot*(256*64) + half*(128*64);
    const unsigned short* gb;
    if (!isB)           gb = xb  + (size_t)(row0 + half*128)*DIM + kt*64;
    else if (half == 0) gb = wkt + (size_t)col0k*DIM + kt*64;
    else                gb = wvt + (size_t)col0k*DIM + kt*64;
    #pragma unroll
    for (int it = 0; it < 2; ++it){
      const int po = (it*512 + tid)*16;
      const int r  = po >> 7;
      const int k2 = (po & 127) ^ ((r & 7) << 4);
      gld_lds16(gb + (size_t)r*DIM + (k2 >> 1), (char*)lb + po);
    }
  };

  #pragma unroll
  for (int u = 0; u < 4; ++u) stage_unit(0, 0, u);

  for (int t = 0; t < 16; ++t){
    const int s = t & 1;
    const char* Ab = (const char*)(Asl + s*(256*64));
    const char* Bb = (const char*)(Bsl + s*(256*64));
    #pragma unroll
    for (int q = 0; q < 4; ++q){
      if (t + 1 < 16) stage_unit(t + 1, s ^ 1, q);
      if (q == 0){
        if (t + 1 < 16) { VMCNT(2); } else { VMCNT(0); }
      }
      SCHED0();
      SBAR();
      SCHED0();
      bf16x8 a[2][2], b[4][2];
      #pragma unroll
      for (int mf = 0; mf < 2; ++mf){
        const int R = wm*128 + (q*2 + mf)*16 + lo;
        #pragma unroll
        for (int ks = 0; ks < 2; ++ks){
          const int K2 = (ks*64 + hi*16) ^ ((R & 7) << 4);
          a[mf][ks] = *reinterpret_cast<const bf16x8*>(Ab + R*128 + K2);
        }
      }
      #pragma unroll
      for (int nf = 0; nf < 4; ++nf){
        const int R = wn*64 + nf*16 + lo;
        #pragma unroll
        for (int ks = 0; ks < 2; ++ks){
          const int K2 = (ks*64 + hi*16) ^ ((R & 7) << 4);
          b[nf][ks] = *reinterpret_cast<const bf16x8*>(Bb + R*128 + K2);
        }
      }
      __builtin_amdgcn_s_setprio(1);
      #pragma unroll
      for (int ks = 0; ks < 2; ++ks)
        #pragma unroll
        for (int mf = 0; mf < 2; ++mf)
          #pragma unroll
          for (int nf = 0; nf < 4; ++nf)
            acc[q*2+mf][nf] = __builtin_amdgcn_mfma_f32_16x16x32_bf16(
                a[mf][ks], b[nf][ks], acc[q*2+mf][nf], 0, 0, 0);
      __builtin_amdgcn_s_setprio(0);
      SCHED0();
      SBAR();
    }
  }

  __syncthreads();
  if (wn >= 2){
    #pragma unroll
    for (int mf = 0; mf < 8; ++mf){
      const int rloc = wm*128 + mf*16 + hi*4;
      #pragma unroll
      for (int nf = 0; nf < 4; ++nf){
        const int cv = (wn - 2)*64 + nf*16 + lo;
        #pragma unroll
        for (int jj = 0; jj < 4; ++jj)
          xch[(size_t)(rloc + jj)*128 + cv] = acc[mf][nf][jj];
      }
    }
  }
  __syncthreads();
  if (wn < 2){
    #pragma unroll
    for (int nf = 0; nf < 4; ++nf){
      const int ck = wn*64 + nf*16 + lo;
      const int c  = col0k + ck;
      const int h  = c >> 7;
      const int d  = c & 127;
      const float bkc = bk[c];
      const float bvc = bv[c];
      #pragma unroll
      for (int mf = 0; mf < 8; ++mf){
        const int rloc = wm*128 + mf*16 + hi*4;
        const int r = row0 + rloc;
        const int n = r >> 11;
        const int sidx = r & 2047;
        ushort4 pk, pv;
        #pragma unroll
        for (int jj = 0; jj < 4; ++jj){
          const float kval = acc[mf][nf][jj] + bkc;
          const float vval = xch[(size_t)(rloc + jj)*128 + ck] + bvc;
          const float ek = __expf(kval);
          ((unsigned short*)&pk)[jj] = f2bf(ek);
          ((unsigned short*)&pv)[jj] = f2bf(ek * vval);
        }
        const size_t idx = ((size_t)h*1024 + n*256 + d) * SEQ + sidx;
        *reinterpret_cast<ushort4*>(&ekb[idx]) = pk;
        *reinterpret_cast<ushort4*>(&ekb[idx + (size_t)128*SEQ]) = pv;
      }
    }
  }
}

// ---------------- AFT causal core: 8-phase, BM=128 BN=256 (den|num), fused division ----------
// (R9/R11 proven version: uniform 34 K-steps/block via triangle pairing {15-p, p})
__global__ __launch_bounds__(512) void k_core(
    const unsigned short* __restrict__ ewb,
    const unsigned short* __restrict__ ekb,
    unsigned short* __restrict__ aftb)
{
  __shared__ __align__(16) char smem[98304];              // A[2][128*64] + B[2][256*64]
  unsigned short* Asl = (unsigned short*)smem;            // 32 KB
  unsigned short* Bsl = (unsigned short*)(smem + 32768);  // 64 KB
  float* xch = (float*)smem;                              // epilogue [128][129] f32

  const int tid  = threadIdx.x;
  const int lane = tid & 63;
  const int lo   = lane & 15;
  const int hi   = lane >> 4;
  const int wid  = tid >> 6;
  const int wm   = wid >> 2;       // 0..1
  const int wn   = wid & 3;        // 0..3
  const int D  = blockIdx.x;
  const int h  = D & 7;
  const int r_ = D >> 3;
  const int p  = r_ >> 2;
  const int n  = r_ & 3;

  const unsigned short* slab = ekb + ((size_t)h*1024 + n*256) * SEQ;

  #pragma unroll
  for (int half = 0; half < 2; ++half){
    const int tt = half ? p : (15 - p);
    const int t0 = tt * 128;
    const int nst = 2*tt + 2;
    const unsigned short* abase = ewb + ((size_t)h*SEQ + t0) * SEQ;

    f32x4 acc[4][4] = {};

    auto stage_unit = [&](int st, int slot, int u){
      const int s0 = st * 64;
      const int po = tid * 16;
      const int r  = po >> 7;
      const int k2 = (po & 127) ^ ((r & 7) << 4);
      if (u < 2){
        unsigned short* lb = Asl + slot*(128*64) + u*(64*64);
        gld_lds16(abase + (size_t)(u*64 + r)*SEQ + s0 + (k2 >> 1), (char*)lb + po);
      } else {
        unsigned short* lb = Bsl + slot*(256*64) + (u-2)*(64*64);
        gld_lds16(slab + (size_t)((u-2)*64 + r)*SEQ + s0 + (k2 >> 1), (char*)lb + po);
      }
    };

    #pragma unroll
    for (int u = 0; u < 6; ++u) stage_unit(0, 0, u);

    for (int t = 0; t < nst; ++t){
      const int s = t & 1;
      const char* Ab = (const char*)(Asl + s*(128*64));
      const char* Bb = (const char*)(Bsl + s*(256*64));
      #pragma unroll
      for (int q = 0; q < 4; ++q){
        if (q < 3 && t + 1 < nst){
          stage_unit(t + 1, s ^ 1, q*2);
          stage_unit(t + 1, s ^ 1, q*2 + 1);
        }
        if (q == 0){
          if (t + 1 < nst) { VMCNT(2); } else { VMCNT(0); }
        }
        SCHED0();
        SBAR();
        SCHED0();
        bf16x8 a[2], b[4][2];
        {
          const int R = wm*64 + q*16 + lo;
          #pragma unroll
          for (int ks = 0; ks < 2; ++ks){
            const int K2 = (ks*64 + hi*16) ^ ((R & 7) << 4);
            a[ks] = *reinterpret_cast<const bf16x8*>(Ab + R*128 + K2);
          }
        }
        #pragma unroll
        for (int nf = 0; nf < 4; ++nf){
          const int R = wn*64 + nf*16 + lo;
          #pragma unroll
          for (int ks = 0; ks < 2; ++ks){
            const int K2 = (ks*64 + hi*16) ^ ((R & 7) << 4);
            b[nf][ks] = *reinterpret_cast<const bf16x8*>(Bb + R*128 + K2);
          }
        }
        __builtin_amdgcn_s_setprio(1);
        #pragma unroll
        for (int ks = 0; ks < 2; ++ks)
          #pragma unroll
          for (int nf = 0; nf < 4; ++nf)
            acc[q][nf] = __builtin_amdgcn_mfma_f32_16x16x32_bf16(
                a[ks], b[nf][ks], acc[q][nf], 0, 0, 0);
        __builtin_amdgcn_s_setprio(0);
        SCHED0();
        SBAR();
      }
    }

    // ---- fused division epilogue ----
    __syncthreads();
    if (wn >= 2){
      #pragma unroll
      for (int mf = 0; mf < 4; ++mf){
        const int rloc = wm*64 + mf*16 + hi*4;
        #pragma unroll
        for (int nf = 0; nf < 4; ++nf){
          const int dv = (wn - 2)*64 + nf*16 + lo;     // num col 0..127
          #pragma unroll
          for (int jj = 0; jj < 4; ++jj)
            xch[(size_t)(rloc + jj)*129 + dv] = acc[mf][nf][jj];
        }
      }
    }
    __syncthreads();
    if (wn < 2){
      #pragma unroll
      for (int nf = 0; nf < 4; ++nf){
        const int d = wn*64 + nf*16 + lo;              // den col 0..127
        #pragma unroll
        for (int mf = 0; mf < 4; ++mf){
          const int rloc = wm*64 + mf*16 + hi*4;
          #pragma unroll
          for (int jj = 0; jj < 4; ++jj){
            const int t = t0 + rloc + jj;
            const float num = xch[(size_t)(rloc + jj)*129 + d];
            aftb[((size_t)n*SEQ + t)*DIM + h*HD + d] = f2bf(num / acc[mf][nf][jj]);
          }
        }
      }
    }
    __syncthreads();   // xch reads done before next half's staging reuses smem
  }
}

// ---------------- output projection: 8-phase, BM=128 BN=256 (R9/R11, proven) ----------------
__global__ __launch_bounds__(512) void k_out(
    const unsigned short* __restrict__ aftb,
    const unsigned short* __restrict__ wot,
    const float* __restrict__ bo,
    float* __restrict__ out)
{
  __shared__ __align__(16) char smem[98304];
  unsigned short* Asl = (unsigned short*)smem;            // [2][128*64]
  unsigned short* Bsl = (unsigned short*)(smem + 32768);  // [2][256*64]

  const int tid  = threadIdx.x;
  const int lane = tid & 63;
  const int lo   = lane & 15;
  const int hi   = lane >> 4;
  const int wid  = tid >> 6;
  const int wm   = wid >> 2;
  const int wn   = wid & 3;
  const int D    = blockIdx.x;
  const int row0 = (D >> 2) * 128;
  const int col0 = (D & 3) * 256;

  f32x4 acc[4][4] = {};

  auto stage_unit = [&](int kt, int slot, int u){
    const int po = tid * 16;
    const int r  = po >> 7;
    const int k2 = (po & 127) ^ ((r & 7) << 4);
    if (u < 2){
      unsigned short* lb = Asl + slot*(128*64) + u*(64*64);
      gld_lds16(aftb + (size_t)(row0 + u*64 + r)*DIM + kt*64 + (k2 >> 1), (char*)lb + po);
    } else {
      unsigned short* lb = Bsl + slot*(256*64) + (u-2)*(64*64);
      gld_lds16(wot + (size_t)(col0 + (u-2)*64 + r)*DIM + kt*64 + (k2 >> 1), (char*)lb + po);
    }
  };

  #pragma unroll
  for (int u = 0; u < 6; ++u) stage_unit(0, 0, u);

  for (int t = 0; t < 16; ++t){
    const int s = t & 1;
    const char* Ab = (const char*)(Asl + s*(128*64));
    const char* Bb = (const char*)(Bsl + s*(256*64));
    #pragma unroll
    for (int q = 0; q < 4; ++q){
      if (q < 3 && t + 1 < 16){
        stage_unit(t + 1, s ^ 1, q*2);
        stage_unit(t + 1, s ^ 1, q*2 + 1);
      }
      if (q == 0){
        if (t + 1 < 16) { VMCNT(2); } else { VMCNT(0); }
      }
      SCHED0();
      SBAR();
      SCHED0();
      bf16x8 a[2], b[4][2];
      {
        const int R = wm*64 + q*16 + lo;
        #pragma unroll
        for (int ks = 0; ks < 2; ++ks){
          const int K2 = (ks*64 + hi*16) ^ ((R & 7) << 4);
          a[ks] = *reinterpret_cast<const bf16x8*>(Ab + R*128 + K2);
        }
      }
      #pragma unroll
      for (int nf = 0; nf < 4; ++nf){
        const int R = wn*64 + nf*16 + lo;
        #pragma unroll
        for (int ks = 0; ks < 2; ++ks){
          const int K2 = (ks*64 + hi*16) ^ ((R & 7) << 4);
          b[nf][ks] = *reinterpret_cast<const bf16x8*>(Bb + R*128 + K2);
        }
      }
      __builtin_amdgcn_s_setprio(1);
      #pragma unroll
      for (int ks = 0; ks < 2; ++ks)
        #pragma unroll
        for (int nf = 0; nf < 4; ++nf)
          acc[q][nf] = __builtin_amdgcn_mfma_f32_16x16x32_bf16(
              a[ks], b[nf][ks], acc[q][nf], 0, 0, 0);
      __builtin_amdgcn_s_setprio(0);
      SCHED0();
      SBAR();
    }
  }

  #pragma unroll
  for (int nf = 0; nf < 4; ++nf){
    const int c = col0 + wn*64 + nf*16 + lo;
    const float boc = bo[c];
    #pragma unroll
    for (int mf = 0; mf < 4; ++mf){
      #pragma unroll
      for (int jj = 0; jj < 4; ++jj){
        const int r = row0 + wm*64 + mf*16 + hi*4 + jj;
        out[(size_t)r*DIM + c] = acc[mf][nf][jj] + boc;
      }
    }
  }
}

extern "C" void kernel_launch(void* const* d_in, const int* in_sizes, int n_in,
                              void* d_out, int out_size, void* d_ws, size_t ws_size,
                              hipStream_t stream){
  const float* x    = (const float*)d_in[0];
  const float* Wk   = (const float*)d_in[1];
  const float* bk   = (const float*)d_in[2];
  const float* Wv   = (const float*)d_in[3];
  const float* bv   = (const float*)d_in[4];
  const float* waft = (const float*)d_in[5];
  const float* Wo   = (const float*)d_in[6];
  const float* bo   = (const float*)d_in[7];
  float* out = (float*)d_out;

  char* w = (char*)d_ws;
  unsigned short* xb   = (unsigned short*)w; w += (size_t)ROWS*DIM*2;       // 16 MB
  unsigned short* wkt  = (unsigned short*)w; w += (size_t)DIM*DIM*2;        // 2 MB
  unsigned short* wvt  = (unsigned short*)w; w += (size_t)DIM*DIM*2;        // 2 MB
  unsigned short* wot  = (unsigned short*)w; w += (size_t)DIM*DIM*2;        // 2 MB
  unsigned short* ekb  = (unsigned short*)w; w += (size_t)HEADS*1024*SEQ*2; // 32 MB
  unsigned short* aftb = (unsigned short*)w; w += (size_t)ROWS*DIM*2;       // 16 MB
  unsigned short* ewb  = (unsigned short*)w; w += (size_t)HEADS*SEQ*SEQ*2;  // 64 MB

  k_prep<<<6912, 256, 0, stream>>>(x, Wk, Wv, Wo, waft, xb, wkt, wvt, wot, ewb);
  k_proj<<<256, 512, 0, stream>>>(xb, wkt, wvt, bk, bv, ekb);
  k_core<<<256, 512, 0, stream>>>(ewb, ekb, aftb);
  k_out<<<256, 512, 0, stream>>>(aftb, wot, bo, out);
}

// Round 15
// 145.999 us; speedup vs baseline: 1.3813x; 1.0983x over previous
//
#include <hip/hip_runtime.h>
#include <hip/hip_bf16.h>
#include <stdint.h>

#define DIM 1024
#define SEQ 2048
#define NB 4
#define HEADS 8
#define HD 128
#define ROWS (NB*SEQ)   // 8192

typedef __attribute__((ext_vector_type(8))) short bf16x8;
typedef __attribute__((ext_vector_type(4))) float f32x4;

#define VMCNT(n) asm volatile("s_waitcnt vmcnt(" #n ")" ::: "memory")
#define SBAR()   __builtin_amdgcn_s_barrier()
#define SCHED0() __builtin_amdgcn_sched_barrier(0)

static __device__ __forceinline__ unsigned short f2bf(float f){
  union { float f; unsigned int u; } x; x.f = f;
  unsigned int r = x.u + 0x7fffu + ((x.u >> 16) & 1u);
  return (unsigned short)(r >> 16);
}

static __device__ __forceinline__ void gld_lds16(const void* g, void* l){
  __builtin_amdgcn_global_load_lds(
      (const __attribute__((address_space(1))) void*)g,
      (__attribute__((address_space(3))) void*)l,
      16, 0, 0);
}

// ---------------- merged prep: cast x | transpose 3 weights | exp(w_aft) per-wave ----------
__global__ void k_prep(const float* __restrict__ x,
                       const float* __restrict__ Wk, const float* __restrict__ Wv,
                       const float* __restrict__ Wo, const float* __restrict__ waft,
                       unsigned short* __restrict__ xb,
                       unsigned short* __restrict__ Tk, unsigned short* __restrict__ Tv,
                       unsigned short* __restrict__ To, unsigned short* __restrict__ ewb){
  __shared__ float tile[64][65];
  const int B = blockIdx.x;
  const int tid = threadIdx.x;
  if (B < 2048){
    for (int i = B*256 + tid; i < ROWS*DIM/4; i += 2048*256){
      const float4 v = reinterpret_cast<const float4*>(x)[i];
      ushort4 o;
      o.x = f2bf(v.x); o.y = f2bf(v.y); o.z = f2bf(v.z); o.w = f2bf(v.w);
      reinterpret_cast<ushort4*>(xb)[i] = o;
    }
  } else if (B < 2816){
    const int D = B - 2048;
    const int z = D >> 8;
    const int rem = D & 255;
    const int bo = (rem & 15) * 64;
    const int bi = (rem >> 4) * 64;
    const float* W = (z == 0) ? Wk : (z == 1) ? Wv : Wo;
    unsigned short* WT = (z == 0) ? Tk : (z == 1) ? Tv : To;
    #pragma unroll
    for (int it = 0; it < 16; ++it){
      int f = it*256 + tid;
      int r = f >> 6, c = f & 63;
      tile[r][c] = W[(size_t)(bi + r) * DIM + bo + c];
    }
    __syncthreads();
    #pragma unroll
    for (int it = 0; it < 16; ++it){
      int f = it*256 + tid;
      int r = f >> 6, c = f & 63;
      WT[(size_t)(bo + r) * DIM + bi + c] = f2bf(tile[c][r]);
    }
  } else {
    const int row = (B - 2816) * 4 + (tid >> 6);
    const int lane = tid & 63;
    const int t = row & 2047;
    const int h = row >> 11;
    const float* src = waft + ((size_t)h*SEQ + t) * SEQ;
    unsigned short* dst = ewb + ((size_t)h*SEQ + t) * SEQ;
    const int smax4 = ((t & ~127) + 128) >> 2;
    for (int i = lane; i < smax4; i += 64){
      const float4 w4 = reinterpret_cast<const float4*>(src)[i];
      const int s = i * 4;
      ushort4 o;
      o.x = (s+0 <= t) ? f2bf(__expf(w4.x)) : (unsigned short)0;
      o.y = (s+1 <= t) ? f2bf(__expf(w4.y)) : (unsigned short)0;
      o.z = (s+2 <= t) ? f2bf(__expf(w4.z)) : (unsigned short)0;
      o.w = (s+3 <= t) ? f2bf(__expf(w4.w)) : (unsigned short)0;
      reinterpret_cast<ushort4*>(dst)[i] = o;
    }
  }
}

// ---------------- fused K/V projection: 8-phase 256^2, B-frags hoisted to q0 ----------------
__global__ __launch_bounds__(512) void k_proj(
    const unsigned short* __restrict__ xb,
    const unsigned short* __restrict__ wkt,
    const unsigned short* __restrict__ wvt,
    const float* __restrict__ bk,
    const float* __restrict__ bv,
    unsigned short* __restrict__ ekb)
{
  __shared__ __align__(16) char smem[131072];
  unsigned short* Asl = (unsigned short*)smem;            // [2][256*64]
  unsigned short* Bsl = (unsigned short*)(smem + 65536);  // [2][256*64]
  float* xch = (float*)smem;                              // epilogue scratch [256][128]

  const int tid  = threadIdx.x;
  const int lane = tid & 63;
  const int lo   = lane & 15;
  const int hi   = lane >> 4;
  const int wid  = tid >> 6;
  const int wm   = wid >> 2;
  const int wn   = wid & 3;
  const int D    = blockIdx.x;
  const int mb   = D >> 3;
  const int cb   = D & 7;
  const int row0 = mb * 256;
  const int col0k = cb * 128;

  f32x4 acc[8][4] = {};

  auto stage_unit = [&](int kt, int slot, int u){
    const int half = u & 1;
    const bool isB = (u >> 1) != 0;
    unsigned short* lb = (isB ? Bsl : Asl) + slot*(256*64) + half*(128*64);
    const unsigned short* gb;
    if (!isB)           gb = xb  + (size_t)(row0 + half*128)*DIM + kt*64;
    else if (half == 0) gb = wkt + (size_t)col0k*DIM + kt*64;
    else                gb = wvt + (size_t)col0k*DIM + kt*64;
    #pragma unroll
    for (int it = 0; it < 2; ++it){
      const int po = (it*512 + tid)*16;
      const int r  = po >> 7;
      const int k2 = (po & 127) ^ ((r & 7) << 4);
      gld_lds16(gb + (size_t)r*DIM + (k2 >> 1), (char*)lb + po);
    }
  };

  #pragma unroll
  for (int u = 0; u < 4; ++u) stage_unit(0, 0, u);

  for (int t = 0; t < 16; ++t){
    const int s = t & 1;
    const char* Ab = (const char*)(Asl + s*(256*64));
    const char* Bb = (const char*)(Bsl + s*(256*64));
    bf16x8 b[4][2];                       // hoisted: loaded at q0, live through q3
    #pragma unroll
    for (int q = 0; q < 4; ++q){
      if (t + 1 < 16) stage_unit(t + 1, s ^ 1, q);
      if (q == 0){
        if (t + 1 < 16) { VMCNT(2); } else { VMCNT(0); }
      }
      SCHED0();
      SBAR();
      SCHED0();
      if (q == 0){
        #pragma unroll
        for (int nf = 0; nf < 4; ++nf){
          const int R = wn*64 + nf*16 + lo;
          #pragma unroll
          for (int ks = 0; ks < 2; ++ks){
            const int K2 = (ks*64 + hi*16) ^ ((R & 7) << 4);
            b[nf][ks] = *reinterpret_cast<const bf16x8*>(Bb + R*128 + K2);
          }
        }
      }
      bf16x8 a[2][2];
      #pragma unroll
      for (int mf = 0; mf < 2; ++mf){
        const int R = wm*128 + (q*2 + mf)*16 + lo;
        #pragma unroll
        for (int ks = 0; ks < 2; ++ks){
          const int K2 = (ks*64 + hi*16) ^ ((R & 7) << 4);
          a[mf][ks] = *reinterpret_cast<const bf16x8*>(Ab + R*128 + K2);
        }
      }
      __builtin_amdgcn_s_setprio(1);
      #pragma unroll
      for (int ks = 0; ks < 2; ++ks)
        #pragma unroll
        for (int mf = 0; mf < 2; ++mf)
          #pragma unroll
          for (int nf = 0; nf < 4; ++nf)
            acc[q*2+mf][nf] = __builtin_amdgcn_mfma_f32_16x16x32_bf16(
                a[mf][ks], b[nf][ks], acc[q*2+mf][nf], 0, 0, 0);
      __builtin_amdgcn_s_setprio(0);
      SCHED0();
      SBAR();
    }
  }

  __syncthreads();
  if (wn >= 2){
    #pragma unroll
    for (int mf = 0; mf < 8; ++mf){
      const int rloc = wm*128 + mf*16 + hi*4;
      #pragma unroll
      for (int nf = 0; nf < 4; ++nf){
        const int cv = (wn - 2)*64 + nf*16 + lo;
        #pragma unroll
        for (int jj = 0; jj < 4; ++jj)
          xch[(size_t)(rloc + jj)*128 + cv] = acc[mf][nf][jj];
      }
    }
  }
  __syncthreads();
  if (wn < 2){
    #pragma unroll
    for (int nf = 0; nf < 4; ++nf){
      const int ck = wn*64 + nf*16 + lo;
      const int c  = col0k + ck;
      const int h  = c >> 7;
      const int d  = c & 127;
      const float bkc = bk[c];
      const float bvc = bv[c];
      #pragma unroll
      for (int mf = 0; mf < 8; ++mf){
        const int rloc = wm*128 + mf*16 + hi*4;
        const int r = row0 + rloc;
        const int n = r >> 11;
        const int sidx = r & 2047;
        ushort4 pk, pv;
        #pragma unroll
        for (int jj = 0; jj < 4; ++jj){
          const float kval = acc[mf][nf][jj] + bkc;
          const float vval = xch[(size_t)(rloc + jj)*128 + ck] + bvc;
          const float ek = __expf(kval);
          ((unsigned short*)&pk)[jj] = f2bf(ek);
          ((unsigned short*)&pv)[jj] = f2bf(ek * vval);
        }
        const size_t idx = ((size_t)h*1024 + n*256 + d) * SEQ + sidx;
        *reinterpret_cast<ushort4*>(&ekb[idx]) = pk;
        *reinterpret_cast<ushort4*>(&ekb[idx + (size_t)128*SEQ]) = pv;
      }
    }
  }
}

// ---------------- AFT causal core: 8-phase, B-frags hoisted to q0, fused division ----------
__global__ __launch_bounds__(512) void k_core(
    const unsigned short* __restrict__ ewb,
    const unsigned short* __restrict__ ekb,
    unsigned short* __restrict__ aftb)
{
  __shared__ __align__(16) char smem[98304];              // A[2][128*64] + B[2][256*64]
  unsigned short* Asl = (unsigned short*)smem;            // 32 KB
  unsigned short* Bsl = (unsigned short*)(smem + 32768);  // 64 KB
  float* xch = (float*)smem;                              // epilogue [128][129] f32

  const int tid  = threadIdx.x;
  const int lane = tid & 63;
  const int lo   = lane & 15;
  const int hi   = lane >> 4;
  const int wid  = tid >> 6;
  const int wm   = wid >> 2;       // 0..1
  const int wn   = wid & 3;        // 0..3
  const int D  = blockIdx.x;
  const int h  = D & 7;
  const int r_ = D >> 3;
  const int p  = r_ >> 2;
  const int n  = r_ & 3;

  const unsigned short* slab = ekb + ((size_t)h*1024 + n*256) * SEQ;

  #pragma unroll
  for (int half = 0; half < 2; ++half){
    const int tt = half ? p : (15 - p);
    const int t0 = tt * 128;
    const int nst = 2*tt + 2;
    const unsigned short* abase = ewb + ((size_t)h*SEQ + t0) * SEQ;

    f32x4 acc[4][4] = {};

    auto stage_unit = [&](int st, int slot, int u){
      const int s0 = st * 64;
      const int po = tid * 16;
      const int r  = po >> 7;
      const int k2 = (po & 127) ^ ((r & 7) << 4);
      if (u < 2){
        unsigned short* lb = Asl + slot*(128*64) + u*(64*64);
        gld_lds16(abase + (size_t)(u*64 + r)*SEQ + s0 + (k2 >> 1), (char*)lb + po);
      } else {
        unsigned short* lb = Bsl + slot*(256*64) + (u-2)*(64*64);
        gld_lds16(slab + (size_t)((u-2)*64 + r)*SEQ + s0 + (k2 >> 1), (char*)lb + po);
      }
    };

    #pragma unroll
    for (int u = 0; u < 6; ++u) stage_unit(0, 0, u);

    for (int t = 0; t < nst; ++t){
      const int s = t & 1;
      const char* Ab = (const char*)(Asl + s*(128*64));
      const char* Bb = (const char*)(Bsl + s*(256*64));
      bf16x8 b[4][2];                     // hoisted: loaded at q0, live through q3
      #pragma unroll
      for (int q = 0; q < 4; ++q){
        if (q < 3 && t + 1 < nst){
          stage_unit(t + 1, s ^ 1, q*2);
          stage_unit(t + 1, s ^ 1, q*2 + 1);
        }
        if (q == 0){
          if (t + 1 < nst) { VMCNT(2); } else { VMCNT(0); }
        }
        SCHED0();
        SBAR();
        SCHED0();
        if (q == 0){
          #pragma unroll
          for (int nf = 0; nf < 4; ++nf){
            const int R = wn*64 + nf*16 + lo;
            #pragma unroll
            for (int ks = 0; ks < 2; ++ks){
              const int K2 = (ks*64 + hi*16) ^ ((R & 7) << 4);
              b[nf][ks] = *reinterpret_cast<const bf16x8*>(Bb + R*128 + K2);
            }
          }
        }
        bf16x8 a[2];
        {
          const int R = wm*64 + q*16 + lo;
          #pragma unroll
          for (int ks = 0; ks < 2; ++ks){
            const int K2 = (ks*64 + hi*16) ^ ((R & 7) << 4);
            a[ks] = *reinterpret_cast<const bf16x8*>(Ab + R*128 + K2);
          }
        }
        __builtin_amdgcn_s_setprio(1);
        #pragma unroll
        for (int ks = 0; ks < 2; ++ks)
          #pragma unroll
          for (int nf = 0; nf < 4; ++nf)
            acc[q][nf] = __builtin_amdgcn_mfma_f32_16x16x32_bf16(
                a[ks], b[nf][ks], acc[q][nf], 0, 0, 0);
        __builtin_amdgcn_s_setprio(0);
        SCHED0();
        SBAR();
      }
    }

    // ---- fused division epilogue ----
    __syncthreads();
    if (wn >= 2){
      #pragma unroll
      for (int mf = 0; mf < 4; ++mf){
        const int rloc = wm*64 + mf*16 + hi*4;
        #pragma unroll
        for (int nf = 0; nf < 4; ++nf){
          const int dv = (wn - 2)*64 + nf*16 + lo;     // num col 0..127
          #pragma unroll
          for (int jj = 0; jj < 4; ++jj)
            xch[(size_t)(rloc + jj)*129 + dv] = acc[mf][nf][jj];
        }
      }
    }
    __syncthreads();
    if (wn < 2){
      #pragma unroll
      for (int nf = 0; nf < 4; ++nf){
        const int d = wn*64 + nf*16 + lo;              // den col 0..127
        #pragma unroll
        for (int mf = 0; mf < 4; ++mf){
          const int rloc = wm*64 + mf*16 + hi*4;
          #pragma unroll
          for (int jj = 0; jj < 4; ++jj){
            const int t = t0 + rloc + jj;
            const float num = xch[(size_t)(rloc + jj)*129 + d];
            aftb[((size_t)n*SEQ + t)*DIM + h*HD + d] = f2bf(num / acc[mf][nf][jj]);
          }
        }
      }
    }
    __syncthreads();   // xch reads done before next half's staging reuses smem
  }
}

// ---------------- output projection: 8-phase, B-frags hoisted to q0 ----------------
__global__ __launch_bounds__(512) void k_out(
    const unsigned short* __restrict__ aftb,
    const unsigned short* __restrict__ wot,
    const float* __restrict__ bo,
    float* __restrict__ out)
{
  __shared__ __align__(16) char smem[98304];
  unsigned short* Asl = (unsigned short*)smem;            // [2][128*64]
  unsigned short* Bsl = (unsigned short*)(smem + 32768);  // [2][256*64]

  const int tid  = threadIdx.x;
  const int lane = tid & 63;
  const int lo   = lane & 15;
  const int hi   = lane >> 4;
  const int wid  = tid >> 6;
  const int wm   = wid >> 2;
  const int wn   = wid & 3;
  const int D    = blockIdx.x;
  const int row0 = (D >> 2) * 128;
  const int col0 = (D & 3) * 256;

  f32x4 acc[4][4] = {};

  auto stage_unit = [&](int kt, int slot, int u){
    const int po = tid * 16;
    const int r  = po >> 7;
    const int k2 = (po & 127) ^ ((r & 7) << 4);
    if (u < 2){
      unsigned short* lb = Asl + slot*(128*64) + u*(64*64);
      gld_lds16(aftb + (size_t)(row0 + u*64 + r)*DIM + kt*64 + (k2 >> 1), (char*)lb + po);
    } else {
      unsigned short* lb = Bsl + slot*(256*64) + (u-2)*(64*64);
      gld_lds16(wot + (size_t)(col0 + (u-2)*64 + r)*DIM + kt*64 + (k2 >> 1), (char*)lb + po);
    }
  };

  #pragma unroll
  for (int u = 0; u < 6; ++u) stage_unit(0, 0, u);

  for (int t = 0; t < 16; ++t){
    const int s = t & 1;
    const char* Ab = (const char*)(Asl + s*(128*64));
    const char* Bb = (const char*)(Bsl + s*(256*64));
    bf16x8 b[4][2];                       // hoisted: loaded at q0, live through q3
    #pragma unroll
    for (int q = 0; q < 4; ++q){
      if (q < 3 && t + 1 < 16){
        stage_unit(t + 1, s ^ 1, q*2);
        stage_unit(t + 1, s ^ 1, q*2 + 1);
      }
      if (q == 0){
        if (t + 1 < 16) { VMCNT(2); } else { VMCNT(0); }
      }
      SCHED0();
      SBAR();
      SCHED0();
      if (q == 0){
        #pragma unroll
        for (int nf = 0; nf < 4; ++nf){
          const int R = wn*64 + nf*16 + lo;
          #pragma unroll
          for (int ks = 0; ks < 2; ++ks){
            const int K2 = (ks*64 + hi*16) ^ ((R & 7) << 4);
            b[nf][ks] = *reinterpret_cast<const bf16x8*>(Bb + R*128 + K2);
          }
        }
      }
      bf16x8 a[2];
      {
        const int R = wm*64 + q*16 + lo;
        #pragma unroll
        for (int ks = 0; ks < 2; ++ks){
          const int K2 = (ks*64 + hi*16) ^ ((R & 7) << 4);
          a[ks] = *reinterpret_cast<const bf16x8*>(Ab + R*128 + K2);
        }
      }
      __builtin_amdgcn_s_setprio(1);
      #pragma unroll
      for (int ks = 0; ks < 2; ++ks)
        #pragma unroll
        for (int nf = 0; nf < 4; ++nf)
          acc[q][nf] = __builtin_amdgcn_mfma_f32_16x16x32_bf16(
              a[ks], b[nf][ks], acc[q][nf], 0, 0, 0);
      __builtin_amdgcn_s_setprio(0);
      SCHED0();
      SBAR();
    }
  }

  #pragma unroll
  for (int nf = 0; nf < 4; ++nf){
    const int c = col0 + wn*64 + nf*16 + lo;
    const float boc = bo[c];
    #pragma unroll
    for (int mf = 0; mf < 4; ++mf){
      #pragma unroll
      for (int jj = 0; jj < 4; ++jj){
        const int r = row0 + wm*64 + mf*16 + hi*4 + jj;
        out[(size_t)r*DIM + c] = acc[mf][nf][jj] + boc;
      }
    }
  }
}

extern "C" void kernel_launch(void* const* d_in, const int* in_sizes, int n_in,
                              void* d_out, int out_size, void* d_ws, size_t ws_size,
                              hipStream_t stream){
  const float* x    = (const float*)d_in[0];
  const float* Wk   = (const float*)d_in[1];
  const float* bk   = (const float*)d_in[2];
  const float* Wv   = (const float*)d_in[3];
  const float* bv   = (const float*)d_in[4];
  const float* waft = (const float*)d_in[5];
  const float* Wo   = (const float*)d_in[6];
  const float* bo   = (const float*)d_in[7];
  float* out = (float*)d_out;

  char* w = (char*)d_ws;
  unsigned short* xb   = (unsigned short*)w; w += (size_t)ROWS*DIM*2;       // 16 MB
  unsigned short* wkt  = (unsigned short*)w; w += (size_t)DIM*DIM*2;        // 2 MB
  unsigned short* wvt  = (unsigned short*)w; w += (size_t)DIM*DIM*2;        // 2 MB
  unsigned short* wot  = (unsigned short*)w; w += (size_t)DIM*DIM*2;        // 2 MB
  unsigned short* ekb  = (unsigned short*)w; w += (size_t)HEADS*1024*SEQ*2; // 32 MB
  unsigned short* aftb = (unsigned short*)w; w += (size_t)ROWS*DIM*2;       // 16 MB
  unsigned short* ewb  = (unsigned short*)w; w += (size_t)HEADS*SEQ*SEQ*2;  // 64 MB

  k_prep<<<6912, 256, 0, stream>>>(x, Wk, Wv, Wo, waft, xb, wkt, wvt, wot, ewb);
  k_proj<<<256, 512, 0, stream>>>(xb, wkt, wvt, bk, bv, ekb);
  k_core<<<256, 512, 0, stream>>>(ewb, ekb, aftb);
  k_out<<<256, 512, 0, stream>>>(aftb, wot, bo, out);
}

// Round 16
// 142.520 us; speedup vs baseline: 1.4150x; 1.0244x over previous
//
#include <hip/hip_runtime.h>
#include <hip/hip_bf16.h>
#include <stdint.h>

#define DIM 1024
#define SEQ 2048
#define NB 4
#define HEADS 8
#define HD 128
#define ROWS (NB*SEQ)   // 8192

typedef __attribute__((ext_vector_type(8))) short bf16x8;
typedef __attribute__((ext_vector_type(4))) float f32x4;

#define VMCNT(n) asm volatile("s_waitcnt vmcnt(" #n ")" ::: "memory")
#define SBAR()   __builtin_amdgcn_s_barrier()
#define SCHED0() __builtin_amdgcn_sched_barrier(0)

static __device__ __forceinline__ unsigned short f2bf(float f){
  union { float f; unsigned int u; } x; x.f = f;
  unsigned int r = x.u + 0x7fffu + ((x.u >> 16) & 1u);
  return (unsigned short)(r >> 16);
}

static __device__ __forceinline__ void gld_lds16(const void* g, void* l){
  __builtin_amdgcn_global_load_lds(
      (const __attribute__((address_space(1))) void*)g,
      (__attribute__((address_space(3))) void*)l,
      16, 0, 0);
}

// ---------------- merged prep: cast x | transpose 3 weights | exp(w_aft) per-wave ----------
__global__ void k_prep(const float* __restrict__ x,
                       const float* __restrict__ Wk, const float* __restrict__ Wv,
                       const float* __restrict__ Wo, const float* __restrict__ waft,
                       unsigned short* __restrict__ xb,
                       unsigned short* __restrict__ Tk, unsigned short* __restrict__ Tv,
                       unsigned short* __restrict__ To, unsigned short* __restrict__ ewb){
  __shared__ float tile[64][65];
  const int B = blockIdx.x;
  const int tid = threadIdx.x;
  if (B < 2048){
    for (int i = B*256 + tid; i < ROWS*DIM/4; i += 2048*256){
      const float4 v = reinterpret_cast<const float4*>(x)[i];
      ushort4 o;
      o.x = f2bf(v.x); o.y = f2bf(v.y); o.z = f2bf(v.z); o.w = f2bf(v.w);
      reinterpret_cast<ushort4*>(xb)[i] = o;
    }
  } else if (B < 2816){
    const int D = B - 2048;
    const int z = D >> 8;
    const int rem = D & 255;
    const int bo = (rem & 15) * 64;
    const int bi = (rem >> 4) * 64;
    const float* W = (z == 0) ? Wk : (z == 1) ? Wv : Wo;
    unsigned short* WT = (z == 0) ? Tk : (z == 1) ? Tv : To;
    #pragma unroll
    for (int it = 0; it < 16; ++it){
      int f = it*256 + tid;
      int r = f >> 6, c = f & 63;
      tile[r][c] = W[(size_t)(bi + r) * DIM + bo + c];
    }
    __syncthreads();
    #pragma unroll
    for (int it = 0; it < 16; ++it){
      int f = it*256 + tid;
      int r = f >> 6, c = f & 63;
      WT[(size_t)(bo + r) * DIM + bi + c] = f2bf(tile[c][r]);
    }
  } else {
    const int row = (B - 2816) * 4 + (tid >> 6);
    const int lane = tid & 63;
    const int t = row & 2047;
    const int h = row >> 11;
    const float* src = waft + ((size_t)h*SEQ + t) * SEQ;
    unsigned short* dst = ewb + ((size_t)h*SEQ + t) * SEQ;
    const int smax4 = ((t & ~127) + 128) >> 2;
    for (int i = lane; i < smax4; i += 64){
      const float4 w4 = reinterpret_cast<const float4*>(src)[i];
      const int s = i * 4;
      ushort4 o;
      o.x = (s+0 <= t) ? f2bf(__expf(w4.x)) : (unsigned short)0;
      o.y = (s+1 <= t) ? f2bf(__expf(w4.y)) : (unsigned short)0;
      o.z = (s+2 <= t) ? f2bf(__expf(w4.z)) : (unsigned short)0;
      o.w = (s+3 <= t) ? f2bf(__expf(w4.w)) : (unsigned short)0;
      reinterpret_cast<ushort4*>(dst)[i] = o;
    }
  }
}

// ---------------- fused K/V projection: 2-phase K-step, B-frags hoisted ----------------
// Per K-step: ph0 {stage A units, VMCNT(4), bar, B-hoist reads + A(q0,q1), 32 MFMA, bar}
//             ph1 {stage B units, bar, A(q2,q3), 32 MFMA, bar}
__global__ __launch_bounds__(512) void k_proj(
    const unsigned short* __restrict__ xb,
    const unsigned short* __restrict__ wkt,
    const unsigned short* __restrict__ wvt,
    const float* __restrict__ bk,
    const float* __restrict__ bv,
    unsigned short* __restrict__ ekb)
{
  __shared__ __align__(16) char smem[131072];
  unsigned short* Asl = (unsigned short*)smem;            // [2][256*64]
  unsigned short* Bsl = (unsigned short*)(smem + 65536);  // [2][256*64]
  float* xch = (float*)smem;                              // epilogue scratch [256][128]

  const int tid  = threadIdx.x;
  const int lane = tid & 63;
  const int lo   = lane & 15;
  const int hi   = lane >> 4;
  const int wid  = tid >> 6;
  const int wm   = wid >> 2;
  const int wn   = wid & 3;
  const int D    = blockIdx.x;
  const int mb   = D >> 3;
  const int cb   = D & 7;
  const int row0 = mb * 256;
  const int col0k = cb * 128;

  f32x4 acc[8][4] = {};

  auto stage_unit = [&](int kt, int slot, int u){
    const int half = u & 1;
    const bool isB = (u >> 1) != 0;
    unsigned short* lb = (isB ? Bsl : Asl) + slot*(256*64) + half*(128*64);
    const unsigned short* gb;
    if (!isB)           gb = xb  + (size_t)(row0 + half*128)*DIM + kt*64;
    else if (half == 0) gb = wkt + (size_t)col0k*DIM + kt*64;
    else                gb = wvt + (size_t)col0k*DIM + kt*64;
    #pragma unroll
    for (int it = 0; it < 2; ++it){
      const int po = (it*512 + tid)*16;
      const int r  = po >> 7;
      const int k2 = (po & 127) ^ ((r & 7) << 4);
      gld_lds16(gb + (size_t)r*DIM + (k2 >> 1), (char*)lb + po);
    }
  };

  #pragma unroll
  for (int u = 0; u < 4; ++u) stage_unit(0, 0, u);

  for (int t = 0; t < 16; ++t){
    const int s = t & 1;
    const char* Ab = (const char*)(Asl + s*(256*64));
    const char* Bb = (const char*)(Bsl + s*(256*64));
    bf16x8 b[4][2];
    #pragma unroll
    for (int ph = 0; ph < 2; ++ph){
      if (t + 1 < 16){
        stage_unit(t + 1, s ^ 1, ph*2);
        stage_unit(t + 1, s ^ 1, ph*2 + 1);
      }
      if (ph == 0){
        if (t + 1 < 16) { VMCNT(4); } else { VMCNT(0); }
      }
      SCHED0();
      SBAR();
      SCHED0();
      if (ph == 0){
        #pragma unroll
        for (int nf = 0; nf < 4; ++nf){
          const int R = wn*64 + nf*16 + lo;
          #pragma unroll
          for (int ks = 0; ks < 2; ++ks){
            const int K2 = (ks*64 + hi*16) ^ ((R & 7) << 4);
            b[nf][ks] = *reinterpret_cast<const bf16x8*>(Bb + R*128 + K2);
          }
        }
      }
      bf16x8 a[4][2];
      #pragma unroll
      for (int mf = 0; mf < 4; ++mf){
        const int R = wm*128 + (ph*4 + mf)*16 + lo;
        #pragma unroll
        for (int ks = 0; ks < 2; ++ks){
          const int K2 = (ks*64 + hi*16) ^ ((R & 7) << 4);
          a[mf][ks] = *reinterpret_cast<const bf16x8*>(Ab + R*128 + K2);
        }
      }
      __builtin_amdgcn_s_setprio(1);
      #pragma unroll
      for (int ks = 0; ks < 2; ++ks)
        #pragma unroll
        for (int mf = 0; mf < 4; ++mf)
          #pragma unroll
          for (int nf = 0; nf < 4; ++nf)
            acc[ph*4+mf][nf] = __builtin_amdgcn_mfma_f32_16x16x32_bf16(
                a[mf][ks], b[nf][ks], acc[ph*4+mf][nf], 0, 0, 0);
      __builtin_amdgcn_s_setprio(0);
      SCHED0();
      SBAR();
    }
  }

  __syncthreads();
  if (wn >= 2){
    #pragma unroll
    for (int mf = 0; mf < 8; ++mf){
      const int rloc = wm*128 + mf*16 + hi*4;
      #pragma unroll
      for (int nf = 0; nf < 4; ++nf){
        const int cv = (wn - 2)*64 + nf*16 + lo;
        #pragma unroll
        for (int jj = 0; jj < 4; ++jj)
          xch[(size_t)(rloc + jj)*128 + cv] = acc[mf][nf][jj];
      }
    }
  }
  __syncthreads();
  if (wn < 2){
    #pragma unroll
    for (int nf = 0; nf < 4; ++nf){
      const int ck = wn*64 + nf*16 + lo;
      const int c  = col0k + ck;
      const int h  = c >> 7;
      const int d  = c & 127;
      const float bkc = bk[c];
      const float bvc = bv[c];
      #pragma unroll
      for (int mf = 0; mf < 8; ++mf){
        const int rloc = wm*128 + mf*16 + hi*4;
        const int r = row0 + rloc;
        const int n = r >> 11;
        const int sidx = r & 2047;
        ushort4 pk, pv;
        #pragma unroll
        for (int jj = 0; jj < 4; ++jj){
          const float kval = acc[mf][nf][jj] + bkc;
          const float vval = xch[(size_t)(rloc + jj)*128 + ck] + bvc;
          const float ek = __expf(kval);
          ((unsigned short*)&pk)[jj] = f2bf(ek);
          ((unsigned short*)&pv)[jj] = f2bf(ek * vval);
        }
        const size_t idx = ((size_t)h*1024 + n*256 + d) * SEQ + sidx;
        *reinterpret_cast<ushort4*>(&ekb[idx]) = pk;
        *reinterpret_cast<ushort4*>(&ekb[idx + (size_t)128*SEQ]) = pv;
      }
    }
  }
}

// ---------------- AFT causal core: 2-phase K-step, B-frags hoisted, fused division ----------
__global__ __launch_bounds__(512) void k_core(
    const unsigned short* __restrict__ ewb,
    const unsigned short* __restrict__ ekb,
    unsigned short* __restrict__ aftb)
{
  __shared__ __align__(16) char smem[98304];              // A[2][128*64] + B[2][256*64]
  unsigned short* Asl = (unsigned short*)smem;            // 32 KB
  unsigned short* Bsl = (unsigned short*)(smem + 32768);  // 64 KB
  float* xch = (float*)smem;                              // epilogue [128][129] f32

  const int tid  = threadIdx.x;
  const int lane = tid & 63;
  const int lo   = lane & 15;
  const int hi   = lane >> 4;
  const int wid  = tid >> 6;
  const int wm   = wid >> 2;       // 0..1
  const int wn   = wid & 3;        // 0..3
  const int D  = blockIdx.x;
  const int h  = D & 7;
  const int r_ = D >> 3;
  const int p  = r_ >> 2;
  const int n  = r_ & 3;

  const unsigned short* slab = ekb + ((size_t)h*1024 + n*256) * SEQ;

  #pragma unroll
  for (int half = 0; half < 2; ++half){
    const int tt = half ? p : (15 - p);
    const int t0 = tt * 128;
    const int nst = 2*tt + 2;
    const unsigned short* abase = ewb + ((size_t)h*SEQ + t0) * SEQ;

    f32x4 acc[4][4] = {};

    auto stage_unit = [&](int st, int slot, int u){
      const int s0 = st * 64;
      const int po = tid * 16;
      const int r  = po >> 7;
      const int k2 = (po & 127) ^ ((r & 7) << 4);
      if (u < 2){
        unsigned short* lb = Asl + slot*(128*64) + u*(64*64);
        gld_lds16(abase + (size_t)(u*64 + r)*SEQ + s0 + (k2 >> 1), (char*)lb + po);
      } else {
        unsigned short* lb = Bsl + slot*(256*64) + (u-2)*(64*64);
        gld_lds16(slab + (size_t)((u-2)*64 + r)*SEQ + s0 + (k2 >> 1), (char*)lb + po);
      }
    };

    #pragma unroll
    for (int u = 0; u < 6; ++u) stage_unit(0, 0, u);

    for (int t = 0; t < nst; ++t){
      const int s = t & 1;
      const char* Ab = (const char*)(Asl + s*(128*64));
      const char* Bb = (const char*)(Bsl + s*(256*64));
      bf16x8 b[4][2];
      #pragma unroll
      for (int ph = 0; ph < 2; ++ph){
        if (t + 1 < nst){
          stage_unit(t + 1, s ^ 1, ph*3);
          stage_unit(t + 1, s ^ 1, ph*3 + 1);
          stage_unit(t + 1, s ^ 1, ph*3 + 2);
        }
        if (ph == 0){
          if (t + 1 < nst) { VMCNT(3); } else { VMCNT(0); }
        }
        SCHED0();
        SBAR();
        SCHED0();
        if (ph == 0){
          #pragma unroll
          for (int nf = 0; nf < 4; ++nf){
            const int R = wn*64 + nf*16 + lo;
            #pragma unroll
            for (int ks = 0; ks < 2; ++ks){
              const int K2 = (ks*64 + hi*16) ^ ((R & 7) << 4);
              b[nf][ks] = *reinterpret_cast<const bf16x8*>(Bb + R*128 + K2);
            }
          }
        }
        bf16x8 a[2][2];
        #pragma unroll
        for (int mf = 0; mf < 2; ++mf){
          const int R = wm*64 + (ph*2 + mf)*16 + lo;
          #pragma unroll
          for (int ks = 0; ks < 2; ++ks){
            const int K2 = (ks*64 + hi*16) ^ ((R & 7) << 4);
            a[mf][ks] = *reinterpret_cast<const bf16x8*>(Ab + R*128 + K2);
          }
        }
        __builtin_amdgcn_s_setprio(1);
        #pragma unroll
        for (int ks = 0; ks < 2; ++ks)
          #pragma unroll
          for (int mf = 0; mf < 2; ++mf)
            #pragma unroll
            for (int nf = 0; nf < 4; ++nf)
              acc[ph*2+mf][nf] = __builtin_amdgcn_mfma_f32_16x16x32_bf16(
                  a[mf][ks], b[nf][ks], acc[ph*2+mf][nf], 0, 0, 0);
        __builtin_amdgcn_s_setprio(0);
        SCHED0();
        SBAR();
      }
    }

    // ---- fused division epilogue ----
    __syncthreads();
    if (wn >= 2){
      #pragma unroll
      for (int mf = 0; mf < 4; ++mf){
        const int rloc = wm*64 + mf*16 + hi*4;
        #pragma unroll
        for (int nf = 0; nf < 4; ++nf){
          const int dv = (wn - 2)*64 + nf*16 + lo;     // num col 0..127
          #pragma unroll
          for (int jj = 0; jj < 4; ++jj)
            xch[(size_t)(rloc + jj)*129 + dv] = acc[mf][nf][jj];
        }
      }
    }
    __syncthreads();
    if (wn < 2){
      #pragma unroll
      for (int nf = 0; nf < 4; ++nf){
        const int d = wn*64 + nf*16 + lo;              // den col 0..127
        #pragma unroll
        for (int mf = 0; mf < 4; ++mf){
          const int rloc = wm*64 + mf*16 + hi*4;
          #pragma unroll
          for (int jj = 0; jj < 4; ++jj){
            const int t = t0 + rloc + jj;
            const float num = xch[(size_t)(rloc + jj)*129 + d];
            aftb[((size_t)n*SEQ + t)*DIM + h*HD + d] = f2bf(num / acc[mf][nf][jj]);
          }
        }
      }
    }
    __syncthreads();   // xch reads done before next half's staging reuses smem
  }
}

// ---------------- output projection: 2-phase K-step, B-frags hoisted ----------------
__global__ __launch_bounds__(512) void k_out(
    const unsigned short* __restrict__ aftb,
    const unsigned short* __restrict__ wot,
    const float* __restrict__ bo,
    float* __restrict__ out)
{
  __shared__ __align__(16) char smem[98304];
  unsigned short* Asl = (unsigned short*)smem;            // [2][128*64]
  unsigned short* Bsl = (unsigned short*)(smem + 32768);  // [2][256*64]

  const int tid  = threadIdx.x;
  const int lane = tid & 63;
  const int lo   = lane & 15;
  const int hi   = lane >> 4;
  const int wid  = tid >> 6;
  const int wm   = wid >> 2;
  const int wn   = wid & 3;
  const int D    = blockIdx.x;
  const int row0 = (D >> 2) * 128;
  const int col0 = (D & 3) * 256;

  f32x4 acc[4][4] = {};

  auto stage_unit = [&](int kt, int slot, int u){
    const int po = tid * 16;
    const int r  = po >> 7;
    const int k2 = (po & 127) ^ ((r & 7) << 4);
    if (u < 2){
      unsigned short* lb = Asl + slot*(128*64) + u*(64*64);
      gld_lds16(aftb + (size_t)(row0 + u*64 + r)*DIM + kt*64 + (k2 >> 1), (char*)lb + po);
    } else {
      unsigned short* lb = Bsl + slot*(256*64) + (u-2)*(64*64);
      gld_lds16(wot + (size_t)(col0 + (u-2)*64 + r)*DIM + kt*64 + (k2 >> 1), (char*)lb + po);
    }
  };

  #pragma unroll
  for (int u = 0; u < 6; ++u) stage_unit(0, 0, u);

  for (int t = 0; t < 16; ++t){
    const int s = t & 1;
    const char* Ab = (const char*)(Asl + s*(128*64));
    const char* Bb = (const char*)(Bsl + s*(256*64));
    bf16x8 b[4][2];
    #pragma unroll
    for (int ph = 0; ph < 2; ++ph){
      if (t + 1 < 16){
        stage_unit(t + 1, s ^ 1, ph*3);
        stage_unit(t + 1, s ^ 1, ph*3 + 1);
        stage_unit(t + 1, s ^ 1, ph*3 + 2);
      }
      if (ph == 0){
        if (t + 1 < 16) { VMCNT(3); } else { VMCNT(0); }
      }
      SCHED0();
      SBAR();
      SCHED0();
      if (ph == 0){
        #pragma unroll
        for (int nf = 0; nf < 4; ++nf){
          const int R = wn*64 + nf*16 + lo;
          #pragma unroll
          for (int ks = 0; ks < 2; ++ks){
            const int K2 = (ks*64 + hi*16) ^ ((R & 7) << 4);
            b[nf][ks] = *reinterpret_cast<const bf16x8*>(Bb + R*128 + K2);
          }
        }
      }
      bf16x8 a[2][2];
      #pragma unroll
      for (int mf = 0; mf < 2; ++mf){
        const int R = wm*64 + (ph*2 + mf)*16 + lo;
        #pragma unroll
        for (int ks = 0; ks < 2; ++ks){
          const int K2 = (ks*64 + hi*16) ^ ((R & 7) << 4);
          a[mf][ks] = *reinterpret_cast<const bf16x8*>(Ab + R*128 + K2);
        }
      }
      __builtin_amdgcn_s_setprio(1);
      #pragma unroll
      for (int ks = 0; ks < 2; ++ks)
        #pragma unroll
        for (int mf = 0; mf < 2; ++mf)
          #pragma unroll
          for (int nf = 0; nf < 4; ++nf)
            acc[ph*2+mf][nf] = __builtin_amdgcn_mfma_f32_16x16x32_bf16(
                a[mf][ks], b[nf][ks], acc[ph*2+mf][nf], 0, 0, 0);
      __builtin_amdgcn_s_setprio(0);
      SCHED0();
      SBAR();
    }
  }

  #pragma unroll
  for (int nf = 0; nf < 4; ++nf){
    const int c = col0 + wn*64 + nf*16 + lo;
    const float boc = bo[c];
    #pragma unroll
    for (int mf = 0; mf < 4; ++mf){
      #pragma unroll
      for (int jj = 0; jj < 4; ++jj){
        const int r = row0 + wm*64 + mf*16 + hi*4 + jj;
        out[(size_t)r*DIM + c] = acc[mf][nf][jj] + boc;
      }
    }
  }
}

extern "C" void kernel_launch(void* const* d_in, const int* in_sizes, int n_in,
                              void* d_out, int out_size, void* d_ws, size_t ws_size,
                              hipStream_t stream){
  const float* x    = (const float*)d_in[0];
  const float* Wk   = (const float*)d_in[1];
  const float* bk   = (const float*)d_in[2];
  const float* Wv   = (const float*)d_in[3];
  const float* bv   = (const float*)d_in[4];
  const float* waft = (const float*)d_in[5];
  const float* Wo   = (const float*)d_in[6];
  const float* bo   = (const float*)d_in[7];
  float* out = (float*)d_out;

  char* w = (char*)d_ws;
  unsigned short* xb   = (unsigned short*)w; w += (size_t)ROWS*DIM*2;       // 16 MB
  unsigned short* wkt  = (unsigned short*)w; w += (size_t)DIM*DIM*2;        // 2 MB
  unsigned short* wvt  = (unsigned short*)w; w += (size_t)DIM*DIM*2;        // 2 MB
  unsigned short* wot  = (unsigned short*)w; w += (size_t)DIM*DIM*2;        // 2 MB
  unsigned short* ekb  = (unsigned short*)w; w += (size_t)HEADS*1024*SEQ*2; // 32 MB
  unsigned short* aftb = (unsigned short*)w; w += (size_t)ROWS*DIM*2;       // 16 MB
  unsigned short* ewb  = (unsigned short*)w; w += (size_t)HEADS*SEQ*SEQ*2;  // 64 MB

  k_prep<<<6912, 256, 0, stream>>>(x, Wk, Wv, Wo, waft, xb, wkt, wvt, wot, ewb);
  k_proj<<<256, 512, 0, stream>>>(xb, wkt, wvt, bk, bv, ekb);
  k_core<<<256, 512, 0, stream>>>(ewb, ekb, aftb);
  k_out<<<256, 512, 0, stream>>>(aftb, wot, bo, out);
}

// Round 17
// 139.459 us; speedup vs baseline: 1.4461x; 1.0219x over previous
//
#include <hip/hip_runtime.h>
#include <hip/hip_bf16.h>
#include <stdint.h>

#define DIM 1024
#define SEQ 2048
#define NB 4
#define HEADS 8
#define HD 128
#define ROWS (NB*SEQ)   // 8192

typedef __attribute__((ext_vector_type(8))) short bf16x8;
typedef __attribute__((ext_vector_type(4))) float f32x4;

#define VMCNT(n) asm volatile("s_waitcnt vmcnt(" #n ")" ::: "memory")
#define SBAR()   __builtin_amdgcn_s_barrier()
#define SCHED0() __builtin_amdgcn_sched_barrier(0)

static __device__ __forceinline__ unsigned short f2bf(float f){
  union { float f; unsigned int u; } x; x.f = f;
  unsigned int r = x.u + 0x7fffu + ((x.u >> 16) & 1u);
  return (unsigned short)(r >> 16);
}

static __device__ __forceinline__ void gld_lds16(const void* g, void* l){
  __builtin_amdgcn_global_load_lds(
      (const __attribute__((address_space(1))) void*)g,
      (__attribute__((address_space(3))) void*)l,
      16, 0, 0);
}

// ---------------- merged prep: cast x | transpose 3 weights | exp(w_aft) per-wave ----------
__global__ void k_prep(const float* __restrict__ x,
                       const float* __restrict__ Wk, const float* __restrict__ Wv,
                       const float* __restrict__ Wo, const float* __restrict__ waft,
                       unsigned short* __restrict__ xb,
                       unsigned short* __restrict__ Tk, unsigned short* __restrict__ Tv,
                       unsigned short* __restrict__ To, unsigned short* __restrict__ ewb){
  __shared__ float tile[64][65];
  const int B = blockIdx.x;
  const int tid = threadIdx.x;
  if (B < 2048){
    for (int i = B*256 + tid; i < ROWS*DIM/4; i += 2048*256){
      const float4 v = reinterpret_cast<const float4*>(x)[i];
      ushort4 o;
      o.x = f2bf(v.x); o.y = f2bf(v.y); o.z = f2bf(v.z); o.w = f2bf(v.w);
      reinterpret_cast<ushort4*>(xb)[i] = o;
    }
  } else if (B < 2816){
    const int D = B - 2048;
    const int z = D >> 8;
    const int rem = D & 255;
    const int bo = (rem & 15) * 64;
    const int bi = (rem >> 4) * 64;
    const float* W = (z == 0) ? Wk : (z == 1) ? Wv : Wo;
    unsigned short* WT = (z == 0) ? Tk : (z == 1) ? Tv : To;
    #pragma unroll
    for (int it = 0; it < 16; ++it){
      int f = it*256 + tid;
      int r = f >> 6, c = f & 63;
      tile[r][c] = W[(size_t)(bi + r) * DIM + bo + c];
    }
    __syncthreads();
    #pragma unroll
    for (int it = 0; it < 16; ++it){
      int f = it*256 + tid;
      int r = f >> 6, c = f & 63;
      WT[(size_t)(bo + r) * DIM + bi + c] = f2bf(tile[c][r]);
    }
  } else {
    const int row = (B - 2816) * 4 + (tid >> 6);
    const int lane = tid & 63;
    const int t = row & 2047;
    const int h = row >> 11;
    const float* src = waft + ((size_t)h*SEQ + t) * SEQ;
    unsigned short* dst = ewb + ((size_t)h*SEQ + t) * SEQ;
    const int smax4 = ((t & ~127) + 128) >> 2;
    for (int i = lane; i < smax4; i += 64){
      const float4 w4 = reinterpret_cast<const float4*>(src)[i];
      const int s = i * 4;
      ushort4 o;
      o.x = (s+0 <= t) ? f2bf(__expf(w4.x)) : (unsigned short)0;
      o.y = (s+1 <= t) ? f2bf(__expf(w4.y)) : (unsigned short)0;
      o.z = (s+2 <= t) ? f2bf(__expf(w4.z)) : (unsigned short)0;
      o.w = (s+3 <= t) ? f2bf(__expf(w4.w)) : (unsigned short)0;
      reinterpret_cast<ushort4*>(dst)[i] = o;
    }
  }
}

// ---------------- fused K/V projection: 1-barrier-pair K-step, B-frags hoisted ----------------
// K-step: {stage u0,u1(t+1), VMCNT(4), bar, B-hoist+A03 reads, stage u2,u3, 32 MFMA,
//          A47 reads, 32 MFMA, bar}. Slot s read-only all step; staging targets s^1.
__global__ __launch_bounds__(512) void k_proj(
    const unsigned short* __restrict__ xb,
    const unsigned short* __restrict__ wkt,
    const unsigned short* __restrict__ wvt,
    const float* __restrict__ bk,
    const float* __restrict__ bv,
    unsigned short* __restrict__ ekb)
{
  __shared__ __align__(16) char smem[131072];
  unsigned short* Asl = (unsigned short*)smem;            // [2][256*64]
  unsigned short* Bsl = (unsigned short*)(smem + 65536);  // [2][256*64]
  float* xch = (float*)smem;                              // epilogue scratch [256][128]

  const int tid  = threadIdx.x;
  const int lane = tid & 63;
  const int lo   = lane & 15;
  const int hi   = lane >> 4;
  const int wid  = tid >> 6;
  const int wm   = wid >> 2;
  const int wn   = wid & 3;
  const int D    = blockIdx.x;
  const int mb   = D >> 3;
  const int cb   = D & 7;
  const int row0 = mb * 256;
  const int col0k = cb * 128;

  f32x4 acc[8][4] = {};

  auto stage_unit = [&](int kt, int slot, int u){
    const int half = u & 1;
    const bool isB = (u >> 1) != 0;
    unsigned short* lb = (isB ? Bsl : Asl) + slot*(256*64) + half*(128*64);
    const unsigned short* gb;
    if (!isB)           gb = xb  + (size_t)(row0 + half*128)*DIM + kt*64;
    else if (half == 0) gb = wkt + (size_t)col0k*DIM + kt*64;
    else                gb = wvt + (size_t)col0k*DIM + kt*64;
    #pragma unroll
    for (int it = 0; it < 2; ++it){
      const int po = (it*512 + tid)*16;
      const int r  = po >> 7;
      const int k2 = (po & 127) ^ ((r & 7) << 4);
      gld_lds16(gb + (size_t)r*DIM + (k2 >> 1), (char*)lb + po);
    }
  };

  #pragma unroll
  for (int u = 0; u < 4; ++u) stage_unit(0, 0, u);

  for (int t = 0; t < 16; ++t){
    const int s = t & 1;
    const bool nxt = (t + 1 < 16);
    const char* Ab = (const char*)(Asl + s*(256*64));
    const char* Bb = (const char*)(Bsl + s*(256*64));
    if (nxt){
      stage_unit(t + 1, s ^ 1, 0);
      stage_unit(t + 1, s ^ 1, 1);
      VMCNT(4);
    } else {
      VMCNT(0);
    }
    SCHED0();
    SBAR();
    SCHED0();
    bf16x8 b[4][2];
    #pragma unroll
    for (int nf = 0; nf < 4; ++nf){
      const int R = wn*64 + nf*16 + lo;
      #pragma unroll
      for (int ks = 0; ks < 2; ++ks){
        const int K2 = (ks*64 + hi*16) ^ ((R & 7) << 4);
        b[nf][ks] = *reinterpret_cast<const bf16x8*>(Bb + R*128 + K2);
      }
    }
    bf16x8 a0[4][2];
    #pragma unroll
    for (int mf = 0; mf < 4; ++mf){
      const int R = wm*128 + mf*16 + lo;
      #pragma unroll
      for (int ks = 0; ks < 2; ++ks){
        const int K2 = (ks*64 + hi*16) ^ ((R & 7) << 4);
        a0[mf][ks] = *reinterpret_cast<const bf16x8*>(Ab + R*128 + K2);
      }
    }
    if (nxt){
      stage_unit(t + 1, s ^ 1, 2);
      stage_unit(t + 1, s ^ 1, 3);
    }
    __builtin_amdgcn_s_setprio(1);
    #pragma unroll
    for (int ks = 0; ks < 2; ++ks)
      #pragma unroll
      for (int mf = 0; mf < 4; ++mf)
        #pragma unroll
        for (int nf = 0; nf < 4; ++nf)
          acc[mf][nf] = __builtin_amdgcn_mfma_f32_16x16x32_bf16(
              a0[mf][ks], b[nf][ks], acc[mf][nf], 0, 0, 0);
    __builtin_amdgcn_s_setprio(0);
    bf16x8 a1[4][2];
    #pragma unroll
    for (int mf = 0; mf < 4; ++mf){
      const int R = wm*128 + (4 + mf)*16 + lo;
      #pragma unroll
      for (int ks = 0; ks < 2; ++ks){
        const int K2 = (ks*64 + hi*16) ^ ((R & 7) << 4);
        a1[mf][ks] = *reinterpret_cast<const bf16x8*>(Ab + R*128 + K2);
      }
    }
    __builtin_amdgcn_s_setprio(1);
    #pragma unroll
    for (int ks = 0; ks < 2; ++ks)
      #pragma unroll
      for (int mf = 0; mf < 4; ++mf)
        #pragma unroll
        for (int nf = 0; nf < 4; ++nf)
          acc[4+mf][nf] = __builtin_amdgcn_mfma_f32_16x16x32_bf16(
              a1[mf][ks], b[nf][ks], acc[4+mf][nf], 0, 0, 0);
    __builtin_amdgcn_s_setprio(0);
    SCHED0();
    SBAR();
  }

  __syncthreads();
  if (wn >= 2){
    #pragma unroll
    for (int mf = 0; mf < 8; ++mf){
      const int rloc = wm*128 + mf*16 + hi*4;
      #pragma unroll
      for (int nf = 0; nf < 4; ++nf){
        const int cv = (wn - 2)*64 + nf*16 + lo;
        #pragma unroll
        for (int jj = 0; jj < 4; ++jj)
          xch[(size_t)(rloc + jj)*128 + cv] = acc[mf][nf][jj];
      }
    }
  }
  __syncthreads();
  if (wn < 2){
    #pragma unroll
    for (int nf = 0; nf < 4; ++nf){
      const int ck = wn*64 + nf*16 + lo;
      const int c  = col0k + ck;
      const int h  = c >> 7;
      const int d  = c & 127;
      const float bkc = bk[c];
      const float bvc = bv[c];
      #pragma unroll
      for (int mf = 0; mf < 8; ++mf){
        const int rloc = wm*128 + mf*16 + hi*4;
        const int r = row0 + rloc;
        const int n = r >> 11;
        const int sidx = r & 2047;
        ushort4 pk, pv;
        #pragma unroll
        for (int jj = 0; jj < 4; ++jj){
          const float kval = acc[mf][nf][jj] + bkc;
          const float vval = xch[(size_t)(rloc + jj)*128 + ck] + bvc;
          const float ek = __expf(kval);
          ((unsigned short*)&pk)[jj] = f2bf(ek);
          ((unsigned short*)&pv)[jj] = f2bf(ek * vval);
        }
        const size_t idx = ((size_t)h*1024 + n*256 + d) * SEQ + sidx;
        *reinterpret_cast<ushort4*>(&ekb[idx]) = pk;
        *reinterpret_cast<ushort4*>(&ekb[idx + (size_t)128*SEQ]) = pv;
      }
    }
  }
}

// ---------------- AFT causal core: 1-barrier-pair K-step, B hoisted, fused division ----------
__global__ __launch_bounds__(512) void k_core(
    const unsigned short* __restrict__ ewb,
    const unsigned short* __restrict__ ekb,
    unsigned short* __restrict__ aftb)
{
  __shared__ __align__(16) char smem[98304];              // A[2][128*64] + B[2][256*64]
  unsigned short* Asl = (unsigned short*)smem;            // 32 KB
  unsigned short* Bsl = (unsigned short*)(smem + 32768);  // 64 KB
  float* xch = (float*)smem;                              // epilogue [128][129] f32

  const int tid  = threadIdx.x;
  const int lane = tid & 63;
  const int lo   = lane & 15;
  const int hi   = lane >> 4;
  const int wid  = tid >> 6;
  const int wm   = wid >> 2;       // 0..1
  const int wn   = wid & 3;        // 0..3
  const int D  = blockIdx.x;
  const int h  = D & 7;
  const int r_ = D >> 3;
  const int p  = r_ >> 2;
  const int n  = r_ & 3;

  const unsigned short* slab = ekb + ((size_t)h*1024 + n*256) * SEQ;

  #pragma unroll
  for (int half = 0; half < 2; ++half){
    const int tt = half ? p : (15 - p);
    const int t0 = tt * 128;
    const int nst = 2*tt + 2;
    const unsigned short* abase = ewb + ((size_t)h*SEQ + t0) * SEQ;

    f32x4 acc[4][4] = {};

    auto stage_unit = [&](int st, int slot, int u){
      const int s0 = st * 64;
      const int po = tid * 16;
      const int r  = po >> 7;
      const int k2 = (po & 127) ^ ((r & 7) << 4);
      if (u < 2){
        unsigned short* lb = Asl + slot*(128*64) + u*(64*64);
        gld_lds16(abase + (size_t)(u*64 + r)*SEQ + s0 + (k2 >> 1), (char*)lb + po);
      } else {
        unsigned short* lb = Bsl + slot*(256*64) + (u-2)*(64*64);
        gld_lds16(slab + (size_t)((u-2)*64 + r)*SEQ + s0 + (k2 >> 1), (char*)lb + po);
      }
    };

    #pragma unroll
    for (int u = 0; u < 6; ++u) stage_unit(0, 0, u);

    for (int t = 0; t < nst; ++t){
      const int s = t & 1;
      const bool nxt = (t + 1 < nst);
      const char* Ab = (const char*)(Asl + s*(128*64));
      const char* Bb = (const char*)(Bsl + s*(256*64));
      if (nxt){
        stage_unit(t + 1, s ^ 1, 0);
        stage_unit(t + 1, s ^ 1, 1);
        stage_unit(t + 1, s ^ 1, 2);
        VMCNT(3);
      } else {
        VMCNT(0);
      }
      SCHED0();
      SBAR();
      SCHED0();
      bf16x8 b[4][2];
      #pragma unroll
      for (int nf = 0; nf < 4; ++nf){
        const int R = wn*64 + nf*16 + lo;
        #pragma unroll
        for (int ks = 0; ks < 2; ++ks){
          const int K2 = (ks*64 + hi*16) ^ ((R & 7) << 4);
          b[nf][ks] = *reinterpret_cast<const bf16x8*>(Bb + R*128 + K2);
        }
      }
      bf16x8 a0[2][2];
      #pragma unroll
      for (int mf = 0; mf < 2; ++mf){
        const int R = wm*64 + mf*16 + lo;
        #pragma unroll
        for (int ks = 0; ks < 2; ++ks){
          const int K2 = (ks*64 + hi*16) ^ ((R & 7) << 4);
          a0[mf][ks] = *reinterpret_cast<const bf16x8*>(Ab + R*128 + K2);
        }
      }
      if (nxt){
        stage_unit(t + 1, s ^ 1, 3);
        stage_unit(t + 1, s ^ 1, 4);
        stage_unit(t + 1, s ^ 1, 5);
      }
      __builtin_amdgcn_s_setprio(1);
      #pragma unroll
      for (int ks = 0; ks < 2; ++ks)
        #pragma unroll
        for (int mf = 0; mf < 2; ++mf)
          #pragma unroll
          for (int nf = 0; nf < 4; ++nf)
            acc[mf][nf] = __builtin_amdgcn_mfma_f32_16x16x32_bf16(
                a0[mf][ks], b[nf][ks], acc[mf][nf], 0, 0, 0);
      __builtin_amdgcn_s_setprio(0);
      bf16x8 a1[2][2];
      #pragma unroll
      for (int mf = 0; mf < 2; ++mf){
        const int R = wm*64 + (2 + mf)*16 + lo;
        #pragma unroll
        for (int ks = 0; ks < 2; ++ks){
          const int K2 = (ks*64 + hi*16) ^ ((R & 7) << 4);
          a1[mf][ks] = *reinterpret_cast<const bf16x8*>(Ab + R*128 + K2);
        }
      }
      __builtin_amdgcn_s_setprio(1);
      #pragma unroll
      for (int ks = 0; ks < 2; ++ks)
        #pragma unroll
        for (int mf = 0; mf < 2; ++mf)
          #pragma unroll
          for (int nf = 0; nf < 4; ++nf)
            acc[2+mf][nf] = __builtin_amdgcn_mfma_f32_16x16x32_bf16(
                a1[mf][ks], b[nf][ks], acc[2+mf][nf], 0, 0, 0);
      __builtin_amdgcn_s_setprio(0);
      SCHED0();
      SBAR();
    }

    // ---- fused division epilogue ----
    __syncthreads();
    if (wn >= 2){
      #pragma unroll
      for (int mf = 0; mf < 4; ++mf){
        const int rloc = wm*64 + mf*16 + hi*4;
        #pragma unroll
        for (int nf = 0; nf < 4; ++nf){
          const int dv = (wn - 2)*64 + nf*16 + lo;     // num col 0..127
          #pragma unroll
          for (int jj = 0; jj < 4; ++jj)
            xch[(size_t)(rloc + jj)*129 + dv] = acc[mf][nf][jj];
        }
      }
    }
    __syncthreads();
    if (wn < 2){
      #pragma unroll
      for (int nf = 0; nf < 4; ++nf){
        const int d = wn*64 + nf*16 + lo;              // den col 0..127
        #pragma unroll
        for (int mf = 0; mf < 4; ++mf){
          const int rloc = wm*64 + mf*16 + hi*4;
          #pragma unroll
          for (int jj = 0; jj < 4; ++jj){
            const int t = t0 + rloc + jj;
            const float num = xch[(size_t)(rloc + jj)*129 + d];
            aftb[((size_t)n*SEQ + t)*DIM + h*HD + d] = f2bf(num / acc[mf][nf][jj]);
          }
        }
      }
    }
    __syncthreads();   // xch reads done before next half's staging reuses smem
  }
}

// ---------------- output projection: 1-barrier-pair K-step, B hoisted ----------------
__global__ __launch_bounds__(512) void k_out(
    const unsigned short* __restrict__ aftb,
    const unsigned short* __restrict__ wot,
    const float* __restrict__ bo,
    float* __restrict__ out)
{
  __shared__ __align__(16) char smem[98304];
  unsigned short* Asl = (unsigned short*)smem;            // [2][128*64]
  unsigned short* Bsl = (unsigned short*)(smem + 32768);  // [2][256*64]

  const int tid  = threadIdx.x;
  const int lane = tid & 63;
  const int lo   = lane & 15;
  const int hi   = lane >> 4;
  const int wid  = tid >> 6;
  const int wm   = wid >> 2;
  const int wn   = wid & 3;
  const int D    = blockIdx.x;
  const int row0 = (D >> 2) * 128;
  const int col0 = (D & 3) * 256;

  f32x4 acc[4][4] = {};

  auto stage_unit = [&](int kt, int slot, int u){
    const int po = tid * 16;
    const int r  = po >> 7;
    const int k2 = (po & 127) ^ ((r & 7) << 4);
    if (u < 2){
      unsigned short* lb = Asl + slot*(128*64) + u*(64*64);
      gld_lds16(aftb + (size_t)(row0 + u*64 + r)*DIM + kt*64 + (k2 >> 1), (char*)lb + po);
    } else {
      unsigned short* lb = Bsl + slot*(256*64) + (u-2)*(64*64);
      gld_lds16(wot + (size_t)(col0 + (u-2)*64 + r)*DIM + kt*64 + (k2 >> 1), (char*)lb + po);
    }
  };

  #pragma unroll
  for (int u = 0; u < 6; ++u) stage_unit(0, 0, u);

  for (int t = 0; t < 16; ++t){
    const int s = t & 1;
    const bool nxt = (t + 1 < 16);
    const char* Ab = (const char*)(Asl + s*(128*64));
    const char* Bb = (const char*)(Bsl + s*(256*64));
    if (nxt){
      stage_unit(t + 1, s ^ 1, 0);
      stage_unit(t + 1, s ^ 1, 1);
      stage_unit(t + 1, s ^ 1, 2);
      VMCNT(3);
    } else {
      VMCNT(0);
    }
    SCHED0();
    SBAR();
    SCHED0();
    bf16x8 b[4][2];
    #pragma unroll
    for (int nf = 0; nf < 4; ++nf){
      const int R = wn*64 + nf*16 + lo;
      #pragma unroll
      for (int ks = 0; ks < 2; ++ks){
        const int K2 = (ks*64 + hi*16) ^ ((R & 7) << 4);
        b[nf][ks] = *reinterpret_cast<const bf16x8*>(Bb + R*128 + K2);
      }
    }
    bf16x8 a0[2][2];
    #pragma unroll
    for (int mf = 0; mf < 2; ++mf){
      const int R = wm*64 + mf*16 + lo;
      #pragma unroll
      for (int ks = 0; ks < 2; ++ks){
        const int K2 = (ks*64 + hi*16) ^ ((R & 7) << 4);
        a0[mf][ks] = *reinterpret_cast<const bf16x8*>(Ab + R*128 + K2);
      }
    }
    if (nxt){
      stage_unit(t + 1, s ^ 1, 3);
      stage_unit(t + 1, s ^ 1, 4);
      stage_unit(t + 1, s ^ 1, 5);
    }
    __builtin_amdgcn_s_setprio(1);
    #pragma unroll
    for (int ks = 0; ks < 2; ++ks)
      #pragma unroll
      for (int mf = 0; mf < 2; ++mf)
        #pragma unroll
        for (int nf = 0; nf < 4; ++nf)
          acc[mf][nf] = __builtin_amdgcn_mfma_f32_16x16x32_bf16(
              a0[mf][ks], b[nf][ks], acc[mf][nf], 0, 0, 0);
    __builtin_amdgcn_s_setprio(0);
    bf16x8 a1[2][2];
    #pragma unroll
    for (int mf = 0; mf < 2; ++mf){
      const int R = wm*64 + (2 + mf)*16 + lo;
      #pragma unroll
      for (int ks = 0; ks < 2; ++ks){
        const int K2 = (ks*64 + hi*16) ^ ((R & 7) << 4);
        a1[mf][ks] = *reinterpret_cast<const bf16x8*>(Ab + R*128 + K2);
      }
    }
    __builtin_amdgcn_s_setprio(1);
    #pragma unroll
    for (int ks = 0; ks < 2; ++ks)
      #pragma unroll
      for (int mf = 0; mf < 2; ++mf)
        #pragma unroll
        for (int nf = 0; nf < 4; ++nf)
          acc[2+mf][nf] = __builtin_amdgcn_mfma_f32_16x16x32_bf16(
              a1[mf][ks], b[nf][ks], acc[2+mf][nf], 0, 0, 0);
    __builtin_amdgcn_s_setprio(0);
    SCHED0();
    SBAR();
  }

  #pragma unroll
  for (int nf = 0; nf < 4; ++nf){
    const int c = col0 + wn*64 + nf*16 + lo;
    const float boc = bo[c];
    #pragma unroll
    for (int mf = 0; mf < 4; ++mf){
      #pragma unroll
      for (int jj = 0; jj < 4; ++jj){
        const int r = row0 + wm*64 + mf*16 + hi*4 + jj;
        out[(size_t)r*DIM + c] = acc[mf][nf][jj] + boc;
      }
    }
  }
}

extern "C" void kernel_launch(void* const* d_in, const int* in_sizes, int n_in,
                              void* d_out, int out_size, void* d_ws, size_t ws_size,
                              hipStream_t stream){
  const float* x    = (const float*)d_in[0];
  const float* Wk   = (const float*)d_in[1];
  const float* bk   = (const float*)d_in[2];
  const float* Wv   = (const float*)d_in[3];
  const float* bv   = (const float*)d_in[4];
  const float* waft = (const float*)d_in[5];
  const float* Wo   = (const float*)d_in[6];
  const float* bo   = (const float*)d_in[7];
  float* out = (float*)d_out;

  char* w = (char*)d_ws;
  unsigned short* xb   = (unsigned short*)w; w += (size_t)ROWS*DIM*2;       // 16 MB
  unsigned short* wkt  = (unsigned short*)w; w += (size_t)DIM*DIM*2;        // 2 MB
  unsigned short* wvt  = (unsigned short*)w; w += (size_t)DIM*DIM*2;        // 2 MB
  unsigned short* wot  = (unsigned short*)w; w += (size_t)DIM*DIM*2;        // 2 MB
  unsigned short* ekb  = (unsigned short*)w; w += (size_t)HEADS*1024*SEQ*2; // 32 MB
  unsigned short* aftb = (unsigned short*)w; w += (size_t)ROWS*DIM*2;       // 16 MB
  unsigned short* ewb  = (unsigned short*)w; w += (size_t)HEADS*SEQ*SEQ*2;  // 64 MB

  k_prep<<<6912, 256, 0, stream>>>(x, Wk, Wv, Wo, waft, xb, wkt, wvt, wot, ewb);
  k_proj<<<256, 512, 0, stream>>>(xb, wkt, wvt, bk, bv, ekb);
  k_core<<<256, 512, 0, stream>>>(ewb, ekb, aftb);
  k_out<<<256, 512, 0, stream>>>(aftb, wot, bo, out);
}

// Round 18
// 137.470 us; speedup vs baseline: 1.4670x; 1.0145x over previous
//
#include <hip/hip_runtime.h>
#include <hip/hip_bf16.h>
#include <stdint.h>

#define DIM 1024
#define SEQ 2048
#define NB 4
#define HEADS 8
#define HD 128
#define ROWS (NB*SEQ)   // 8192

typedef __attribute__((ext_vector_type(8))) short bf16x8;
typedef __attribute__((ext_vector_type(4))) float f32x4;

#define VMCNT(n) asm volatile("s_waitcnt vmcnt(" #n ")" ::: "memory")
#define SBAR()   __builtin_amdgcn_s_barrier()
#define SCHED0() __builtin_amdgcn_sched_barrier(0)

static __device__ __forceinline__ unsigned short f2bf(float f){
  union { float f; unsigned int u; } x; x.f = f;
  unsigned int r = x.u + 0x7fffu + ((x.u >> 16) & 1u);
  return (unsigned short)(r >> 16);
}

static __device__ __forceinline__ void gld_lds16(const void* g, void* l){
  __builtin_amdgcn_global_load_lds(
      (const __attribute__((address_space(1))) void*)g,
      (__attribute__((address_space(3))) void*)l,
      16, 0, 0);
}

// ---------------- merged prep: cast x | transpose 3 weights | exp(w_aft) per-wave ----------
__global__ void k_prep(const float* __restrict__ x,
                       const float* __restrict__ Wk, const float* __restrict__ Wv,
                       const float* __restrict__ Wo, const float* __restrict__ waft,
                       unsigned short* __restrict__ xb,
                       unsigned short* __restrict__ Tk, unsigned short* __restrict__ Tv,
                       unsigned short* __restrict__ To, unsigned short* __restrict__ ewb){
  __shared__ float tile[64][65];
  const int B = blockIdx.x;
  const int tid = threadIdx.x;
  if (B < 2048){
    for (int i = B*256 + tid; i < ROWS*DIM/4; i += 2048*256){
      const float4 v = reinterpret_cast<const float4*>(x)[i];
      ushort4 o;
      o.x = f2bf(v.x); o.y = f2bf(v.y); o.z = f2bf(v.z); o.w = f2bf(v.w);
      reinterpret_cast<ushort4*>(xb)[i] = o;
    }
  } else if (B < 2816){
    const int D = B - 2048;
    const int z = D >> 8;
    const int rem = D & 255;
    const int bo = (rem & 15) * 64;
    const int bi = (rem >> 4) * 64;
    const float* W = (z == 0) ? Wk : (z == 1) ? Wv : Wo;
    unsigned short* WT = (z == 0) ? Tk : (z == 1) ? Tv : To;
    #pragma unroll
    for (int it = 0; it < 16; ++it){
      int f = it*256 + tid;
      int r = f >> 6, c = f & 63;
      tile[r][c] = W[(size_t)(bi + r) * DIM + bo + c];
    }
    __syncthreads();
    #pragma unroll
    for (int it = 0; it < 16; ++it){
      int f = it*256 + tid;
      int r = f >> 6, c = f & 63;
      WT[(size_t)(bo + r) * DIM + bi + c] = f2bf(tile[c][r]);
    }
  } else {
    const int row = (B - 2816) * 4 + (tid >> 6);
    const int lane = tid & 63;
    const int t = row & 2047;
    const int h = row >> 11;
    const float* src = waft + ((size_t)h*SEQ + t) * SEQ;
    unsigned short* dst = ewb + ((size_t)h*SEQ + t) * SEQ;
    const int smax4 = ((t & ~127) + 128) >> 2;
    for (int i = lane; i < smax4; i += 64){
      const float4 w4 = reinterpret_cast<const float4*>(src)[i];
      const int s = i * 4;
      ushort4 o;
      o.x = (s+0 <= t) ? f2bf(__expf(w4.x)) : (unsigned short)0;
      o.y = (s+1 <= t) ? f2bf(__expf(w4.y)) : (unsigned short)0;
      o.z = (s+2 <= t) ? f2bf(__expf(w4.z)) : (unsigned short)0;
      o.w = (s+3 <= t) ? f2bf(__expf(w4.w)) : (unsigned short)0;
      reinterpret_cast<ushort4*>(dst)[i] = o;
    }
  }
}

// ---------------- fused K/V projection: 1-barrier-pair K-step, B-frags hoisted (R17) --------
__global__ __launch_bounds__(512) void k_proj(
    const unsigned short* __restrict__ xb,
    const unsigned short* __restrict__ wkt,
    const unsigned short* __restrict__ wvt,
    const float* __restrict__ bk,
    const float* __restrict__ bv,
    unsigned short* __restrict__ ekb)
{
  __shared__ __align__(16) char smem[131072];
  unsigned short* Asl = (unsigned short*)smem;            // [2][256*64]
  unsigned short* Bsl = (unsigned short*)(smem + 65536);  // [2][256*64]
  float* xch = (float*)smem;                              // epilogue scratch [256][128]

  const int tid  = threadIdx.x;
  const int lane = tid & 63;
  const int lo   = lane & 15;
  const int hi   = lane >> 4;
  const int wid  = tid >> 6;
  const int wm   = wid >> 2;
  const int wn   = wid & 3;
  const int D    = blockIdx.x;
  const int mb   = D >> 3;
  const int cb   = D & 7;
  const int row0 = mb * 256;
  const int col0k = cb * 128;

  f32x4 acc[8][4] = {};

  auto stage_unit = [&](int kt, int slot, int u){
    const int half = u & 1;
    const bool isB = (u >> 1) != 0;
    unsigned short* lb = (isB ? Bsl : Asl) + slot*(256*64) + half*(128*64);
    const unsigned short* gb;
    if (!isB)           gb = xb  + (size_t)(row0 + half*128)*DIM + kt*64;
    else if (half == 0) gb = wkt + (size_t)col0k*DIM + kt*64;
    else                gb = wvt + (size_t)col0k*DIM + kt*64;
    #pragma unroll
    for (int it = 0; it < 2; ++it){
      const int po = (it*512 + tid)*16;
      const int r  = po >> 7;
      const int k2 = (po & 127) ^ ((r & 7) << 4);
      gld_lds16(gb + (size_t)r*DIM + (k2 >> 1), (char*)lb + po);
    }
  };

  #pragma unroll
  for (int u = 0; u < 4; ++u) stage_unit(0, 0, u);

  for (int t = 0; t < 16; ++t){
    const int s = t & 1;
    const bool nxt = (t + 1 < 16);
    const char* Ab = (const char*)(Asl + s*(256*64));
    const char* Bb = (const char*)(Bsl + s*(256*64));
    if (nxt){
      stage_unit(t + 1, s ^ 1, 0);
      stage_unit(t + 1, s ^ 1, 1);
      VMCNT(4);
    } else {
      VMCNT(0);
    }
    SCHED0();
    SBAR();
    SCHED0();
    bf16x8 b[4][2];
    #pragma unroll
    for (int nf = 0; nf < 4; ++nf){
      const int R = wn*64 + nf*16 + lo;
      #pragma unroll
      for (int ks = 0; ks < 2; ++ks){
        const int K2 = (ks*64 + hi*16) ^ ((R & 7) << 4);
        b[nf][ks] = *reinterpret_cast<const bf16x8*>(Bb + R*128 + K2);
      }
    }
    bf16x8 a0[4][2];
    #pragma unroll
    for (int mf = 0; mf < 4; ++mf){
      const int R = wm*128 + mf*16 + lo;
      #pragma unroll
      for (int ks = 0; ks < 2; ++ks){
        const int K2 = (ks*64 + hi*16) ^ ((R & 7) << 4);
        a0[mf][ks] = *reinterpret_cast<const bf16x8*>(Ab + R*128 + K2);
      }
    }
    if (nxt){
      stage_unit(t + 1, s ^ 1, 2);
      stage_unit(t + 1, s ^ 1, 3);
    }
    __builtin_amdgcn_s_setprio(1);
    #pragma unroll
    for (int ks = 0; ks < 2; ++ks)
      #pragma unroll
      for (int mf = 0; mf < 4; ++mf)
        #pragma unroll
        for (int nf = 0; nf < 4; ++nf)
          acc[mf][nf] = __builtin_amdgcn_mfma_f32_16x16x32_bf16(
              a0[mf][ks], b[nf][ks], acc[mf][nf], 0, 0, 0);
    __builtin_amdgcn_s_setprio(0);
    bf16x8 a1[4][2];
    #pragma unroll
    for (int mf = 0; mf < 4; ++mf){
      const int R = wm*128 + (4 + mf)*16 + lo;
      #pragma unroll
      for (int ks = 0; ks < 2; ++ks){
        const int K2 = (ks*64 + hi*16) ^ ((R & 7) << 4);
        a1[mf][ks] = *reinterpret_cast<const bf16x8*>(Ab + R*128 + K2);
      }
    }
    __builtin_amdgcn_s_setprio(1);
    #pragma unroll
    for (int ks = 0; ks < 2; ++ks)
      #pragma unroll
      for (int mf = 0; mf < 4; ++mf)
        #pragma unroll
        for (int nf = 0; nf < 4; ++nf)
          acc[4+mf][nf] = __builtin_amdgcn_mfma_f32_16x16x32_bf16(
              a1[mf][ks], b[nf][ks], acc[4+mf][nf], 0, 0, 0);
    __builtin_amdgcn_s_setprio(0);
    SCHED0();
    SBAR();
  }

  __syncthreads();
  if (wn >= 2){
    #pragma unroll
    for (int mf = 0; mf < 8; ++mf){
      const int rloc = wm*128 + mf*16 + hi*4;
      #pragma unroll
      for (int nf = 0; nf < 4; ++nf){
        const int cv = (wn - 2)*64 + nf*16 + lo;
        #pragma unroll
        for (int jj = 0; jj < 4; ++jj)
          xch[(size_t)(rloc + jj)*128 + cv] = acc[mf][nf][jj];
      }
    }
  }
  __syncthreads();
  if (wn < 2){
    #pragma unroll
    for (int nf = 0; nf < 4; ++nf){
      const int ck = wn*64 + nf*16 + lo;
      const int c  = col0k + ck;
      const int h  = c >> 7;
      const int d  = c & 127;
      const float bkc = bk[c];
      const float bvc = bv[c];
      #pragma unroll
      for (int mf = 0; mf < 8; ++mf){
        const int rloc = wm*128 + mf*16 + hi*4;
        const int r = row0 + rloc;
        const int n = r >> 11;
        const int sidx = r & 2047;
        ushort4 pk, pv;
        #pragma unroll
        for (int jj = 0; jj < 4; ++jj){
          const float kval = acc[mf][nf][jj] + bkc;
          const float vval = xch[(size_t)(rloc + jj)*128 + ck] + bvc;
          const float ek = __expf(kval);
          ((unsigned short*)&pk)[jj] = f2bf(ek);
          ((unsigned short*)&pv)[jj] = f2bf(ek * vval);
        }
        const size_t idx = ((size_t)h*1024 + n*256 + d) * SEQ + sidx;
        *reinterpret_cast<ushort4*>(&ekb[idx]) = pk;
        *reinterpret_cast<ushort4*>(&ekb[idx + (size_t)128*SEQ]) = pv;
      }
    }
  }
}

// ---------------- AFT causal core: 3-slot, ONE barrier per K-step, fused division ----------
// Window t: {stage(t+1)->slot (t+1)%3, VMCNT(6), bar, reads slot t%3, MFMA x2}.
// Safety: slot (t+1)%3 last read in window t-2; every wave pre-bar(t) passed bar(t-1),
// which follows its window t-2 reads. vmcnt(6): only t+1's 6 units newer than tile t's.
__global__ __launch_bounds__(512) void k_core(
    const unsigned short* __restrict__ ewb,
    const unsigned short* __restrict__ ekb,
    unsigned short* __restrict__ aftb)
{
  __shared__ __align__(16) char smem[147456];             // A[3][128*64] + B[3][256*64]
  unsigned short* Asl = (unsigned short*)smem;            // 48 KB
  unsigned short* Bsl = (unsigned short*)(smem + 49152);  // 96 KB
  float* xch = (float*)smem;                              // epilogue [128][129] f32

  const int tid  = threadIdx.x;
  const int lane = tid & 63;
  const int lo   = lane & 15;
  const int hi   = lane >> 4;
  const int wid  = tid >> 6;
  const int wm   = wid >> 2;       // 0..1
  const int wn   = wid & 3;        // 0..3
  const int D  = blockIdx.x;
  const int h  = D & 7;
  const int r_ = D >> 3;
  const int p  = r_ >> 2;
  const int n  = r_ & 3;

  const unsigned short* slab = ekb + ((size_t)h*1024 + n*256) * SEQ;

  #pragma unroll
  for (int half = 0; half < 2; ++half){
    const int tt = half ? p : (15 - p);
    const int t0 = tt * 128;
    const int nst = 2*tt + 2;
    const unsigned short* abase = ewb + ((size_t)h*SEQ + t0) * SEQ;

    f32x4 acc[4][4] = {};

    auto stage_unit = [&](int st, int slot, int u){
      const int s0 = st * 64;
      const int po = tid * 16;
      const int r  = po >> 7;
      const int k2 = (po & 127) ^ ((r & 7) << 4);
      if (u < 2){
        unsigned short* lb = Asl + slot*(128*64) + u*(64*64);
        gld_lds16(abase + (size_t)(u*64 + r)*SEQ + s0 + (k2 >> 1), (char*)lb + po);
      } else {
        unsigned short* lb = Bsl + slot*(256*64) + (u-2)*(64*64);
        gld_lds16(slab + (size_t)((u-2)*64 + r)*SEQ + s0 + (k2 >> 1), (char*)lb + po);
      }
    };

    #pragma unroll
    for (int u = 0; u < 6; ++u) stage_unit(0, 0, u);

    int slot_cur = 0;
    for (int t = 0; t < nst; ++t){
      const bool nxt = (t + 1 < nst);
      const int slot_nxt = (slot_cur == 2) ? 0 : slot_cur + 1;
      const char* Ab = (const char*)(Asl + slot_cur*(128*64));
      const char* Bb = (const char*)(Bsl + slot_cur*(256*64));
      if (nxt){
        #pragma unroll
        for (int u = 0; u < 6; ++u) stage_unit(t + 1, slot_nxt, u);
        VMCNT(6);
      } else {
        VMCNT(0);
      }
      SCHED0();
      SBAR();
      SCHED0();
      bf16x8 b[4][2];
      #pragma unroll
      for (int nf = 0; nf < 4; ++nf){
        const int R = wn*64 + nf*16 + lo;
        #pragma unroll
        for (int ks = 0; ks < 2; ++ks){
          const int K2 = (ks*64 + hi*16) ^ ((R & 7) << 4);
          b[nf][ks] = *reinterpret_cast<const bf16x8*>(Bb + R*128 + K2);
        }
      }
      bf16x8 a0[2][2];
      #pragma unroll
      for (int mf = 0; mf < 2; ++mf){
        const int R = wm*64 + mf*16 + lo;
        #pragma unroll
        for (int ks = 0; ks < 2; ++ks){
          const int K2 = (ks*64 + hi*16) ^ ((R & 7) << 4);
          a0[mf][ks] = *reinterpret_cast<const bf16x8*>(Ab + R*128 + K2);
        }
      }
      __builtin_amdgcn_s_setprio(1);
      #pragma unroll
      for (int ks = 0; ks < 2; ++ks)
        #pragma unroll
        for (int mf = 0; mf < 2; ++mf)
          #pragma unroll
          for (int nf = 0; nf < 4; ++nf)
            acc[mf][nf] = __builtin_amdgcn_mfma_f32_16x16x32_bf16(
                a0[mf][ks], b[nf][ks], acc[mf][nf], 0, 0, 0);
      __builtin_amdgcn_s_setprio(0);
      bf16x8 a1[2][2];
      #pragma unroll
      for (int mf = 0; mf < 2; ++mf){
        const int R = wm*64 + (2 + mf)*16 + lo;
        #pragma unroll
        for (int ks = 0; ks < 2; ++ks){
          const int K2 = (ks*64 + hi*16) ^ ((R & 7) << 4);
          a1[mf][ks] = *reinterpret_cast<const bf16x8*>(Ab + R*128 + K2);
        }
      }
      __builtin_amdgcn_s_setprio(1);
      #pragma unroll
      for (int ks = 0; ks < 2; ++ks)
        #pragma unroll
        for (int mf = 0; mf < 2; ++mf)
          #pragma unroll
          for (int nf = 0; nf < 4; ++nf)
            acc[2+mf][nf] = __builtin_amdgcn_mfma_f32_16x16x32_bf16(
                a1[mf][ks], b[nf][ks], acc[2+mf][nf], 0, 0, 0);
      __builtin_amdgcn_s_setprio(0);
      slot_cur = slot_nxt;
    }

    // ---- fused division epilogue ----
    __syncthreads();
    if (wn >= 2){
      #pragma unroll
      for (int mf = 0; mf < 4; ++mf){
        const int rloc = wm*64 + mf*16 + hi*4;
        #pragma unroll
        for (int nf = 0; nf < 4; ++nf){
          const int dv = (wn - 2)*64 + nf*16 + lo;     // num col 0..127
          #pragma unroll
          for (int jj = 0; jj < 4; ++jj)
            xch[(size_t)(rloc + jj)*129 + dv] = acc[mf][nf][jj];
        }
      }
    }
    __syncthreads();
    if (wn < 2){
      #pragma unroll
      for (int nf = 0; nf < 4; ++nf){
        const int d = wn*64 + nf*16 + lo;              // den col 0..127
        #pragma unroll
        for (int mf = 0; mf < 4; ++mf){
          const int rloc = wm*64 + mf*16 + hi*4;
          #pragma unroll
          for (int jj = 0; jj < 4; ++jj){
            const int t = t0 + rloc + jj;
            const float num = xch[(size_t)(rloc + jj)*129 + d];
            aftb[((size_t)n*SEQ + t)*DIM + h*HD + d] = f2bf(num / acc[mf][nf][jj]);
          }
        }
      }
    }
    __syncthreads();   // xch reads done before next half's staging reuses smem
  }
}

// ---------------- output projection: 3-slot, ONE barrier per K-step ----------------
__global__ __launch_bounds__(512) void k_out(
    const unsigned short* __restrict__ aftb,
    const unsigned short* __restrict__ wot,
    const float* __restrict__ bo,
    float* __restrict__ out)
{
  __shared__ __align__(16) char smem[147456];
  unsigned short* Asl = (unsigned short*)smem;            // [3][128*64]
  unsigned short* Bsl = (unsigned short*)(smem + 49152);  // [3][256*64]

  const int tid  = threadIdx.x;
  const int lane = tid & 63;
  const int lo   = lane & 15;
  const int hi   = lane >> 4;
  const int wid  = tid >> 6;
  const int wm   = wid >> 2;
  const int wn   = wid & 3;
  const int D    = blockIdx.x;
  const int row0 = (D >> 2) * 128;
  const int col0 = (D & 3) * 256;

  f32x4 acc[4][4] = {};

  auto stage_unit = [&](int kt, int slot, int u){
    const int po = tid * 16;
    const int r  = po >> 7;
    const int k2 = (po & 127) ^ ((r & 7) << 4);
    if (u < 2){
      unsigned short* lb = Asl + slot*(128*64) + u*(64*64);
      gld_lds16(aftb + (size_t)(row0 + u*64 + r)*DIM + kt*64 + (k2 >> 1), (char*)lb + po);
    } else {
      unsigned short* lb = Bsl + slot*(256*64) + (u-2)*(64*64);
      gld_lds16(wot + (size_t)(col0 + (u-2)*64 + r)*DIM + kt*64 + (k2 >> 1), (char*)lb + po);
    }
  };

  #pragma unroll
  for (int u = 0; u < 6; ++u) stage_unit(0, 0, u);

  int slot_cur = 0;
  for (int t = 0; t < 16; ++t){
    const bool nxt = (t + 1 < 16);
    const int slot_nxt = (slot_cur == 2) ? 0 : slot_cur + 1;
    const char* Ab = (const char*)(Asl + slot_cur*(128*64));
    const char* Bb = (const char*)(Bsl + slot_cur*(256*64));
    if (nxt){
      #pragma unroll
      for (int u = 0; u < 6; ++u) stage_unit(t + 1, slot_nxt, u);
      VMCNT(6);
    } else {
      VMCNT(0);
    }
    SCHED0();
    SBAR();
    SCHED0();
    bf16x8 b[4][2];
    #pragma unroll
    for (int nf = 0; nf < 4; ++nf){
      const int R = wn*64 + nf*16 + lo;
      #pragma unroll
      for (int ks = 0; ks < 2; ++ks){
        const int K2 = (ks*64 + hi*16) ^ ((R & 7) << 4);
        b[nf][ks] = *reinterpret_cast<const bf16x8*>(Bb + R*128 + K2);
      }
    }
    bf16x8 a0[2][2];
    #pragma unroll
    for (int mf = 0; mf < 2; ++mf){
      const int R = wm*64 + mf*16 + lo;
      #pragma unroll
      for (int ks = 0; ks < 2; ++ks){
        const int K2 = (ks*64 + hi*16) ^ ((R & 7) << 4);
        a0[mf][ks] = *reinterpret_cast<const bf16x8*>(Ab + R*128 + K2);
      }
    }
    __builtin_amdgcn_s_setprio(1);
    #pragma unroll
    for (int ks = 0; ks < 2; ++ks)
      #pragma unroll
      for (int mf = 0; mf < 2; ++mf)
        #pragma unroll
        for (int nf = 0; nf < 4; ++nf)
          acc[mf][nf] = __builtin_amdgcn_mfma_f32_16x16x32_bf16(
              a0[mf][ks], b[nf][ks], acc[mf][nf], 0, 0, 0);
    __builtin_amdgcn_s_setprio(0);
    bf16x8 a1[2][2];
    #pragma unroll
    for (int mf = 0; mf < 2; ++mf){
      const int R = wm*64 + (2 + mf)*16 + lo;
      #pragma unroll
      for (int ks = 0; ks < 2; ++ks){
        const int K2 = (ks*64 + hi*16) ^ ((R & 7) << 4);
        a1[mf][ks] = *reinterpret_cast<const bf16x8*>(Ab + R*128 + K2);
      }
    }
    __builtin_amdgcn_s_setprio(1);
    #pragma unroll
    for (int ks = 0; ks < 2; ++ks)
      #pragma unroll
      for (int mf = 0; mf < 2; ++mf)
        #pragma unroll
        for (int nf = 0; nf < 4; ++nf)
          acc[2+mf][nf] = __builtin_amdgcn_mfma_f32_16x16x32_bf16(
              a1[mf][ks], b[nf][ks], acc[2+mf][nf], 0, 0, 0);
    __builtin_amdgcn_s_setprio(0);
    slot_cur = slot_nxt;
  }

  #pragma unroll
  for (int nf = 0; nf < 4; ++nf){
    const int c = col0 + wn*64 + nf*16 + lo;
    const float boc = bo[c];
    #pragma unroll
    for (int mf = 0; mf < 4; ++mf){
      #pragma unroll
      for (int jj = 0; jj < 4; ++jj){
        const int r = row0 + wm*64 + mf*16 + hi*4 + jj;
        out[(size_t)r*DIM + c] = acc[mf][nf][jj] + boc;
      }
    }
  }
}

extern "C" void kernel_launch(void* const* d_in, const int* in_sizes, int n_in,
                              void* d_out, int out_size, void* d_ws, size_t ws_size,
                              hipStream_t stream){
  const float* x    = (const float*)d_in[0];
  const float* Wk   = (const float*)d_in[1];
  const float* bk   = (const float*)d_in[2];
  const float* Wv   = (const float*)d_in[3];
  const float* bv   = (const float*)d_in[4];
  const float* waft = (const float*)d_in[5];
  const float* Wo   = (const float*)d_in[6];
  const float* bo   = (const float*)d_in[7];
  float* out = (float*)d_out;

  char* w = (char*)d_ws;
  unsigned short* xb   = (unsigned short*)w; w += (size_t)ROWS*DIM*2;       // 16 MB
  unsigned short* wkt  = (unsigned short*)w; w += (size_t)DIM*DIM*2;        // 2 MB
  unsigned short* wvt  = (unsigned short*)w; w += (size_t)DIM*DIM*2;        // 2 MB
  unsigned short* wot  = (unsigned short*)w; w += (size_t)DIM*DIM*2;        // 2 MB
  unsigned short* ekb  = (unsigned short*)w; w += (size_t)HEADS*1024*SEQ*2; // 32 MB
  unsigned short* aftb = (unsigned short*)w; w += (size_t)ROWS*DIM*2;       // 16 MB
  unsigned short* ewb  = (unsigned short*)w; w += (size_t)HEADS*SEQ*SEQ*2;  // 64 MB

  k_prep<<<6912, 256, 0, stream>>>(x, Wk, Wv, Wo, waft, xb, wkt, wvt, wot, ewb);
  k_proj<<<256, 512, 0, stream>>>(xb, wkt, wvt, bk, bv, ekb);
  k_core<<<256, 512, 0, stream>>>(ewb, ekb, aftb);
  k_out<<<256, 512, 0, stream>>>(aftb, wot, bo, out);
}